// Round 1
// baseline (2587.212 us; speedup 1.0000x reference)
//
#include <hip/hip_runtime.h>
#include <hip/hip_bf16.h>

namespace {

constexpr int kNV = 160000;
constexpr int kNE = 480000;
constexpr int kB  = 16;
constexpr int kV  = 10000;

// ---------------- CSR build ----------------

__global__ __launch_bounds__(256) void count_deg_kernel(const int2* __restrict__ edges,
                                                        int* __restrict__ deg) {
  int i = blockIdx.x * 256 + threadIdx.x;
  if (i < kNE) {
    int2 e = edges[i];
    atomicAdd(&deg[e.x], 1);
    atomicAdd(&deg[e.y], 1);
  }
}

__global__ __launch_bounds__(1024) void scan_kernel(const int* __restrict__ deg,
                                                    int* __restrict__ rowptr,
                                                    int* __restrict__ cursor) {
  __shared__ int sums[1024];
  const int tid = threadIdx.x;
  constexpr int per = (kNV + 1023) / 1024;  // 157
  int start = tid * per;
  int end = start + per;
  if (end > kNV) end = kNV;
  if (start > kNV) start = kNV;
  int s = 0;
  for (int i = start; i < end; ++i) s += deg[i];
  sums[tid] = s;
  __syncthreads();
  // Hillis-Steele inclusive scan over 1024 block sums
  for (int off = 1; off < 1024; off <<= 1) {
    int v = (tid >= off) ? sums[tid - off] : 0;
    __syncthreads();
    sums[tid] += v;
    __syncthreads();
  }
  if (tid == 0) rowptr[kNV] = sums[1023];
  int base = sums[tid] - s;  // exclusive prefix for this chunk
  for (int i = start; i < end; ++i) {
    rowptr[i] = base;
    cursor[i] = base;
    base += deg[i];
  }
}

__global__ __launch_bounds__(256) void fill_adj_kernel(const int2* __restrict__ edges,
                                                       int* __restrict__ cursor,
                                                       int* __restrict__ adj) {
  int i = blockIdx.x * 256 + threadIdx.x;
  if (i < kNE) {
    int2 e = edges[i];
    int p = atomicAdd(&cursor[e.x], 1);
    adj[p] = e.y;
    int q = atomicAdd(&cursor[e.y], 1);
    adj[q] = e.x;
  }
}

// ---------------- Layer 0: din=3 -> dout=128 ----------------

__global__ __launch_bounds__(256) void gcn_layer0_kernel(
    const float* __restrict__ x, const int* __restrict__ rowptr,
    const int* __restrict__ adj, const float* __restrict__ w0,
    const float* __restrict__ b0, const float* __restrict__ w1,
    const float* __restrict__ b1, float* __restrict__ y) {
  constexpr int TM = 32, DOUT = 128;
  __shared__ float xs[TM][3];
  __shared__ float ags[TM][3];
  __shared__ float degs[TM];
  const int v0 = blockIdx.x * TM;
  const int tid = threadIdx.x;
  if (tid < TM * 3) xs[tid / 3][tid % 3] = x[(size_t)v0 * 3 + tid];
  if (tid < TM) {
    int v = v0 + tid;
    int beg = rowptr[v], end = rowptr[v + 1];
    float a0 = 0.f, a1 = 0.f, a2 = 0.f;
    for (int j = beg; j < end; ++j) {
      int u = adj[j];
      a0 += x[(size_t)u * 3 + 0];
      a1 += x[(size_t)u * 3 + 1];
      a2 += x[(size_t)u * 3 + 2];
    }
    ags[tid][0] = a0;
    ags[tid][1] = a1;
    ags[tid][2] = a2;
    degs[tid] = (float)(end - beg);
  }
  __syncthreads();
  const int o = tid & 127;
  const int half = tid >> 7;
  const float w00 = w0[o * 3], w01 = w0[o * 3 + 1], w02 = w0[o * 3 + 2];
  const float w10 = w1[o * 3], w11 = w1[o * 3 + 1], w12 = w1[o * 3 + 2];
  const float bb0 = b0[o], bb1 = b1[o];
  for (int m = half; m < TM; m += 2) {
    float r = bb0 + degs[m] * bb1
            + xs[m][0] * w00 + xs[m][1] * w01 + xs[m][2] * w02
            + ags[m][0] * w10 + ags[m][1] * w11 + ags[m][2] * w12;
    y[(size_t)(v0 + m) * DOUT + o] = fmaxf(r, 0.f);
  }
}

// ---------------- Generic layer: din in {128,256}, dout=256 ----------------
// out[v] = relu( x[v]@w0.T + b0 + (sum_{u in N(v)} x[u])@w1.T + deg(v)*b1 )
// POOL=true: instead of storing the row, accumulate relu'd rows into
// pooled[b][o] (mean over kV vertices per batch element).

template <int DIN, bool POOL>
__global__ __launch_bounds__(256) void gcn_layer_kernel(
    const float* __restrict__ x, const int* __restrict__ rowptr,
    const int* __restrict__ adj, const float* __restrict__ w0,
    const float* __restrict__ b0, const float* __restrict__ w1,
    const float* __restrict__ b1, float* __restrict__ out) {
  constexpr int DOUT = 256;
  constexpr int TM = 16;
  __shared__ float xs[TM][DIN];
  __shared__ float ags[TM][DIN];
  const int v0 = blockIdx.x * TM;
  const int tid = threadIdx.x;

  // Stage x tile (coalesced: xs is contiguous, rows are contiguous in x).
  for (int idx = tid; idx < TM * DIN; idx += 256) {
    (&xs[0][0])[idx] = x[(size_t)v0 * DIN + idx];
  }

  // Neighbor aggregation: wave w handles vertices [w*4, w*4+4); 64 lanes
  // cover one full row per pass with float4/float2 loads.
  const int wave = tid >> 6, lane = tid & 63;
  constexpr int VEC = DIN / 64;  // 2 (din=128) or 4 (din=256)
  constexpr int MPW = TM / 4;
  for (int mi = 0; mi < MPW; ++mi) {
    int m = wave * MPW + mi;
    int v = v0 + m;
    int beg = rowptr[v], end = rowptr[v + 1];
    float r[VEC];
#pragma unroll
    for (int k = 0; k < VEC; ++k) r[k] = 0.f;
    for (int j = beg; j < end; ++j) {
      int u = adj[j];
      const float* xu = x + (size_t)u * DIN + lane * VEC;
      if constexpr (VEC == 4) {
        float4 t = *reinterpret_cast<const float4*>(xu);
        r[0] += t.x; r[1] += t.y; r[2] += t.z; r[3] += t.w;
      } else {
        float2 t = *reinterpret_cast<const float2*>(xu);
        r[0] += t.x; r[1] += t.y;
      }
    }
#pragma unroll
    for (int k = 0; k < VEC; ++k) ags[m][lane * VEC + k] = r[k];
  }
  __syncthreads();

  const int o = tid;  // DOUT == blockDim.x == 256
  const float bb0 = b0[o], bb1 = b1[o];
  float acc[TM];
#pragma unroll
  for (int m = 0; m < TM; ++m) {
    float dg = (float)(rowptr[v0 + m + 1] - rowptr[v0 + m]);
    acc[m] = bb0 + dg * bb1;
  }
  const float4* w0r = reinterpret_cast<const float4*>(w0 + (size_t)o * DIN);
  const float4* w1r = reinterpret_cast<const float4*>(w1 + (size_t)o * DIN);
  for (int d4 = 0; d4 < DIN / 4; ++d4) {
    float4 wa = w0r[d4];
    float4 wb = w1r[d4];
#pragma unroll
    for (int m = 0; m < TM; ++m) {
      float4 xv = *reinterpret_cast<const float4*>(&xs[m][d4 * 4]);
      float4 av = *reinterpret_cast<const float4*>(&ags[m][d4 * 4]);
      acc[m] += xv.x * wa.x + xv.y * wa.y + xv.z * wa.z + xv.w * wa.w
              + av.x * wb.x + av.y * wb.y + av.z * wb.z + av.w * wb.w;
    }
  }

  if constexpr (POOL) {
    float s = 0.f;
#pragma unroll
    for (int m = 0; m < TM; ++m) s += fmaxf(acc[m], 0.f);
    const int b = v0 / kV;  // blocks never straddle batches (kV % TM == 0)
    atomicAdd(&out[b * DOUT + o], s * (1.0f / (float)kV));
  } else {
    float* yr = out + (size_t)v0 * DOUT + o;
#pragma unroll
    for (int m = 0; m < TM; ++m) {
      yr[(size_t)m * DOUT] = fmaxf(acc[m], 0.f);
    }
  }
}

// ---------------- MLP head ----------------

__global__ __launch_bounds__(256) void fc1_kernel(const float* __restrict__ pooled,
                                                  const float* __restrict__ w,
                                                  const float* __restrict__ b,
                                                  float* __restrict__ h) {
  __shared__ float ps[256];
  const int bb = blockIdx.x;
  const int o = blockIdx.y * 256 + threadIdx.x;
  ps[threadIdx.x] = pooled[bb * 256 + threadIdx.x];
  __syncthreads();
  const float4* wr = reinterpret_cast<const float4*>(w + (size_t)o * 256);
  float acc = b[o];
  for (int d4 = 0; d4 < 64; ++d4) {
    float4 wv = wr[d4];
    acc += ps[d4 * 4 + 0] * wv.x + ps[d4 * 4 + 1] * wv.y
         + ps[d4 * 4 + 2] * wv.z + ps[d4 * 4 + 3] * wv.w;
  }
  h[bb * 1024 + o] = fmaxf(acc, 0.f);
}

__global__ __launch_bounds__(256) void fc2_kernel(const float* __restrict__ h,
                                                  const float* __restrict__ w,
                                                  const float* __restrict__ b,
                                                  float* __restrict__ out) {
  const int t = threadIdx.x;
  if (t >= kB * 10) return;
  const int bb = t / 10, c = t % 10;
  const float* hr = h + bb * 1024;
  const float* wr = w + c * 1024;
  float acc = b[c];
  for (int k = 0; k < 1024; ++k) acc += hr[k] * wr[k];
  out[t] = acc;
}

}  // namespace

extern "C" void kernel_launch(void* const* d_in, const int* in_sizes, int n_in,
                              void* d_out, int out_size, void* d_ws, size_t ws_size,
                              hipStream_t stream) {
  const float* verts = (const float*)d_in[0];
  const int2*  edges = (const int2*)d_in[1];
  const float* g0w0 = (const float*)d_in[2];
  const float* g0b0 = (const float*)d_in[3];
  const float* g0w1 = (const float*)d_in[4];
  const float* g0b1 = (const float*)d_in[5];
  const float* g1w0 = (const float*)d_in[6];
  const float* g1b0 = (const float*)d_in[7];
  const float* g1w1 = (const float*)d_in[8];
  const float* g1b1 = (const float*)d_in[9];
  const float* g2w0 = (const float*)d_in[10];
  const float* g2b0 = (const float*)d_in[11];
  const float* g2w1 = (const float*)d_in[12];
  const float* g2b1 = (const float*)d_in[13];
  const float* fc1w = (const float*)d_in[14];
  const float* fc1b = (const float*)d_in[15];
  const float* fc2w = (const float*)d_in[16];
  const float* fc2b = (const float*)d_in[17];
  float* outp = (float*)d_out;

  // Workspace partition (~252 MB total)
  char* p = (char*)d_ws;
  auto alloc = [&](size_t bytes) {
    char* r = p;
    p += (bytes + 255) & ~(size_t)255;
    return r;
  };
  float* x1     = (float*)alloc((size_t)kNV * 128 * sizeof(float));   //  82 MB
  float* x2     = (float*)alloc((size_t)kNV * 256 * sizeof(float));   // 164 MB
  int*   deg    = (int*)alloc((size_t)kNV * sizeof(int));
  int*   rowptr = (int*)alloc((size_t)(kNV + 1) * sizeof(int));
  int*   cursor = (int*)alloc((size_t)kNV * sizeof(int));
  int*   adj    = (int*)alloc((size_t)2 * kNE * sizeof(int));
  float* pooled = (float*)alloc((size_t)kB * 256 * sizeof(float));
  float* h      = (float*)alloc((size_t)kB * 1024 * sizeof(float));

  hipMemsetAsync(deg, 0, (size_t)kNV * sizeof(int), stream);
  hipMemsetAsync(pooled, 0, (size_t)kB * 256 * sizeof(float), stream);

  // CSR build (per call; edges constant across the 3 layers)
  count_deg_kernel<<<(kNE + 255) / 256, 256, 0, stream>>>(edges, deg);
  scan_kernel<<<1, 1024, 0, stream>>>(deg, rowptr, cursor);
  fill_adj_kernel<<<(kNE + 255) / 256, 256, 0, stream>>>(edges, cursor, adj);

  // GCN layers (aggregate-then-transform formulation)
  gcn_layer0_kernel<<<kNV / 32, 256, 0, stream>>>(verts, rowptr, adj,
                                                  g0w0, g0b0, g0w1, g0b1, x1);
  gcn_layer_kernel<128, false><<<kNV / 16, 256, 0, stream>>>(
      x1, rowptr, adj, g1w0, g1b0, g1w1, g1b1, x2);
  gcn_layer_kernel<256, true><<<kNV / 16, 256, 0, stream>>>(
      x2, rowptr, adj, g2w0, g2b0, g2w1, g2b1, pooled);

  // MLP head
  fc1_kernel<<<dim3(kB, 4), 256, 0, stream>>>(pooled, fc1w, fc1b, h);
  fc2_kernel<<<1, 256, 0, stream>>>(h, fc2w, fc2b, outp);
}

// Round 2
// 959.074 us; speedup vs baseline: 2.6976x; 2.6976x over previous
//
#include <hip/hip_runtime.h>
#include <hip/hip_bf16.h>

typedef __attribute__((ext_vector_type(8))) short short8;
typedef __attribute__((ext_vector_type(4))) float f32x4;

namespace {

constexpr int kNV = 160000;
constexpr int kNE = 480000;
constexpr int kB  = 16;
constexpr int kV  = 10000;

__device__ inline unsigned short f2b(float f) {  // fp32 -> bf16 RNE
  unsigned u = __float_as_uint(f);
  unsigned r = u + 0x7fffu + ((u >> 16) & 1u);
  return (unsigned short)(r >> 16);
}
__device__ inline float blo(unsigned u) { return __uint_as_float(u << 16); }
__device__ inline float bhi(unsigned u) { return __uint_as_float(u & 0xffff0000u); }

// ---------------- CSR build ----------------

__global__ __launch_bounds__(256) void count_deg_kernel(const int2* __restrict__ edges,
                                                        int* __restrict__ deg) {
  int i = blockIdx.x * 256 + threadIdx.x;
  if (i < kNE) {
    int2 e = edges[i];
    atomicAdd(&deg[e.x], 1);
    atomicAdd(&deg[e.y], 1);
  }
}

__global__ __launch_bounds__(1024) void scan_kernel(const int* __restrict__ deg,
                                                    int* __restrict__ rowptr,
                                                    int* __restrict__ cursor) {
  __shared__ int sums[1024];
  const int tid = threadIdx.x;
  constexpr int per = (kNV + 1023) / 1024;  // 157
  int start = tid * per;
  int end = start + per;
  if (end > kNV) end = kNV;
  if (start > kNV) start = kNV;
  int s = 0;
  for (int i = start; i < end; ++i) s += deg[i];
  sums[tid] = s;
  __syncthreads();
  for (int off = 1; off < 1024; off <<= 1) {
    int v = (tid >= off) ? sums[tid - off] : 0;
    __syncthreads();
    sums[tid] += v;
    __syncthreads();
  }
  if (tid == 0) rowptr[kNV] = sums[1023];
  int base = sums[tid] - s;
  for (int i = start; i < end; ++i) {
    rowptr[i] = base;
    cursor[i] = base;
    base += deg[i];
  }
}

__global__ __launch_bounds__(256) void fill_adj_kernel(const int2* __restrict__ edges,
                                                       int* __restrict__ cursor,
                                                       int* __restrict__ adj) {
  int i = blockIdx.x * 256 + threadIdx.x;
  if (i < kNE) {
    int2 e = edges[i];
    int p = atomicAdd(&cursor[e.x], 1);
    adj[p] = e.y;
    int q = atomicAdd(&cursor[e.y], 1);
    adj[q] = e.x;
  }
}

// ---------------- Weight prep: Wcat[o][k] = [w0[o][:] | w1[o][:]] in bf16 ----

__global__ __launch_bounds__(256) void prep_wcat_kernel(const float* __restrict__ w0,
                                                        const float* __restrict__ w1,
                                                        unsigned short* __restrict__ wcat,
                                                        int din) {
  const int o = blockIdx.x;
  const int K = 2 * din;
  for (int k = threadIdx.x; k < din; k += 256) {
    wcat[(size_t)o * K + k]       = f2b(w0[(size_t)o * din + k]);
    wcat[(size_t)o * K + din + k] = f2b(w1[(size_t)o * din + k]);
  }
}

// ---------------- Layer 0: din=3 -> dout=128, bf16 output ----------------

__global__ __launch_bounds__(256) void gcn_layer0_kernel(
    const float* __restrict__ x, const int* __restrict__ rowptr,
    const int* __restrict__ adj, const float* __restrict__ w0,
    const float* __restrict__ b0, const float* __restrict__ w1,
    const float* __restrict__ b1, unsigned short* __restrict__ y) {
  constexpr int TM = 32, DOUT = 128;
  __shared__ float xs[TM][3];
  __shared__ float ags[TM][3];
  __shared__ float degs[TM];
  const int v0 = blockIdx.x * TM;
  const int tid = threadIdx.x;
  if (tid < TM * 3) xs[tid / 3][tid % 3] = x[(size_t)v0 * 3 + tid];
  if (tid < TM) {
    int v = v0 + tid;
    int beg = rowptr[v], end = rowptr[v + 1];
    float a0 = 0.f, a1 = 0.f, a2 = 0.f;
    for (int j = beg; j < end; ++j) {
      int u = adj[j];
      a0 += x[(size_t)u * 3 + 0];
      a1 += x[(size_t)u * 3 + 1];
      a2 += x[(size_t)u * 3 + 2];
    }
    ags[tid][0] = a0;
    ags[tid][1] = a1;
    ags[tid][2] = a2;
    degs[tid] = (float)(end - beg);
  }
  __syncthreads();
  const int o = tid & 127;
  const int half = tid >> 7;
  const float w00 = w0[o * 3], w01 = w0[o * 3 + 1], w02 = w0[o * 3 + 2];
  const float w10 = w1[o * 3], w11 = w1[o * 3 + 1], w12 = w1[o * 3 + 2];
  const float bb0 = b0[o], bb1 = b1[o];
  for (int m = half; m < TM; m += 2) {
    float r = bb0 + degs[m] * bb1
            + xs[m][0] * w00 + xs[m][1] * w01 + xs[m][2] * w02
            + ags[m][0] * w10 + ags[m][1] * w11 + ags[m][2] * w12;
    y[(size_t)(v0 + m) * DOUT + o] = f2b(fmaxf(r, 0.f));
  }
}

// ---------------- Fused GCN layer via MFMA (bf16) ----------------
// LDS tile: TM rows of [ x[v] (DIN bf16) | agg[v] (DIN bf16) ], K = 2*DIN.
// out[v] = relu( tile[v] @ Wcat.T + b0 + deg(v)*b1 );  POOL: mean-pool per batch.

template <int DIN, bool POOL>
__global__ __launch_bounds__(256) void gcn_mfma_kernel(
    const unsigned short* __restrict__ x, const int* __restrict__ rowptr,
    const int* __restrict__ adj, const unsigned short* __restrict__ wcat,
    const float* __restrict__ b0, const float* __restrict__ b1,
    void* __restrict__ out) {
  constexpr int TM = 32;
  constexpr int K = 2 * DIN;
  constexpr int ROWB = K * 2;  // bytes per LDS row
  __shared__ __align__(16) char lds[TM * ROWB];
  __shared__ float degs_s[TM];

  const int tid = threadIdx.x;
  const int lane = tid & 63;
  const int wave = tid >> 6;

  int v0, valid, batch;
  if constexpr (POOL) {
    batch = blockIdx.y;
    v0 = batch * kV + blockIdx.x * TM;
    valid = min(TM, kV - (int)blockIdx.x * TM);
  } else {
    batch = 0;
    v0 = blockIdx.x * TM;
    valid = TM;
  }

  auto swz = [&](int row, int off) { return row * ROWB + (off ^ ((row & 7) << 4)); };

  // ---- stage self rows (zero-fill rows beyond `valid`) ----
  constexpr int SLOTS = ROWB / 16;
  constexpr int SELF_SLOTS = (DIN * 2) / 16;
  for (int c = tid; c < TM * SLOTS; c += 256) {
    int row = c / SLOTS, slot = c % SLOTS;
    if (slot < SELF_SLOTS) {
      uint4 val;
      if (row < valid)
        val = *(const uint4*)(x + (size_t)(v0 + row) * DIN + slot * 8);
      else
        val = make_uint4(0, 0, 0, 0);
      *(uint4*)(lds + swz(row, slot * 16)) = val;
    } else if (row >= valid) {
      *(uint4*)(lds + swz(row, slot * 16)) = make_uint4(0, 0, 0, 0);
    }
  }

  // ---- neighbor aggregation: wave w owns vertices [w*8, w*8+8) ----
  const char* xb = (const char*)x;
  for (int mi = 0; mi < TM / 4; ++mi) {
    int m = wave * (TM / 4) + mi;
    if (m >= valid) break;
    int v = v0 + m;
    int beg = rowptr[v], end = rowptr[v + 1];
    if (lane == 0) degs_s[m] = (float)(end - beg);
    if constexpr (DIN == 128) {
      float r0 = 0.f, r1 = 0.f;
      int j = beg;
      for (; j + 4 <= end; j += 4) {
        int u0 = adj[j], u1 = adj[j + 1], u2 = adj[j + 2], u3 = adj[j + 3];
        unsigned a0 = *(const unsigned*)(xb + (size_t)u0 * 256 + lane * 4);
        unsigned a1 = *(const unsigned*)(xb + (size_t)u1 * 256 + lane * 4);
        unsigned a2 = *(const unsigned*)(xb + (size_t)u2 * 256 + lane * 4);
        unsigned a3 = *(const unsigned*)(xb + (size_t)u3 * 256 + lane * 4);
        r0 += blo(a0) + blo(a1) + blo(a2) + blo(a3);
        r1 += bhi(a0) + bhi(a1) + bhi(a2) + bhi(a3);
      }
      for (; j < end; ++j) {
        unsigned a = *(const unsigned*)(xb + (size_t)adj[j] * 256 + lane * 4);
        r0 += blo(a);
        r1 += bhi(a);
      }
      unsigned pk = ((unsigned)f2b(r1) << 16) | (unsigned)f2b(r0);
      *(unsigned*)(lds + swz(m, DIN * 2 + lane * 4)) = pk;
    } else {  // DIN == 256
      float r0 = 0.f, r1 = 0.f, r2 = 0.f, r3 = 0.f;
      int j = beg;
      for (; j + 4 <= end; j += 4) {
        int u0 = adj[j], u1 = adj[j + 1], u2 = adj[j + 2], u3 = adj[j + 3];
        uint2 a0 = *(const uint2*)(xb + (size_t)u0 * 512 + lane * 8);
        uint2 a1 = *(const uint2*)(xb + (size_t)u1 * 512 + lane * 8);
        uint2 a2 = *(const uint2*)(xb + (size_t)u2 * 512 + lane * 8);
        uint2 a3 = *(const uint2*)(xb + (size_t)u3 * 512 + lane * 8);
        r0 += blo(a0.x) + blo(a1.x) + blo(a2.x) + blo(a3.x);
        r1 += bhi(a0.x) + bhi(a1.x) + bhi(a2.x) + bhi(a3.x);
        r2 += blo(a0.y) + blo(a1.y) + blo(a2.y) + blo(a3.y);
        r3 += bhi(a0.y) + bhi(a1.y) + bhi(a2.y) + bhi(a3.y);
      }
      for (; j < end; ++j) {
        uint2 a = *(const uint2*)(xb + (size_t)adj[j] * 512 + lane * 8);
        r0 += blo(a.x);
        r1 += bhi(a.x);
        r2 += blo(a.y);
        r3 += bhi(a.y);
      }
      uint2 pk;
      pk.x = ((unsigned)f2b(r1) << 16) | (unsigned)f2b(r0);
      pk.y = ((unsigned)f2b(r3) << 16) | (unsigned)f2b(r2);
      *(uint2*)(lds + swz(m, DIN * 2 + lane * 8)) = pk;
    }
  }
  __syncthreads();

  // ---- MFMA transform: wave w computes channels [w*64, w*64+64), all 32 rows
  const int col = lane & 15;
  const int kgrp = lane >> 4;
  const int obase = wave * 64;
  f32x4 acc[2][4] = {};
  for (int k0 = 0; k0 < K; k0 += 32) {
    const int kb = (k0 + kgrp * 8) * 2;
    short8 a0 = *(const short8*)(lds + swz(col, kb));
    short8 a1 = *(const short8*)(lds + swz(col + 16, kb));
    const unsigned short* wp = wcat + (size_t)(obase + col) * K + k0 + kgrp * 8;
#pragma unroll
    for (int nf = 0; nf < 4; ++nf) {
      short8 bfrag = *(const short8*)(wp + (size_t)nf * 16 * K);
      acc[0][nf] = __builtin_amdgcn_mfma_f32_16x16x32_bf16(a0, bfrag, acc[0][nf], 0, 0, 0);
      acc[1][nf] = __builtin_amdgcn_mfma_f32_16x16x32_bf16(a1, bfrag, acc[1][nf], 0, 0, 0);
    }
  }

  // ---- epilogue: C/D map col=lane&15, row=(lane>>4)*4+reg (+16 for mf=1) ----
  const int rb = kgrp * 4;
  if constexpr (POOL) {
    float* pooled = (float*)out;
#pragma unroll
    for (int nf = 0; nf < 4; ++nf) {
      int o = obase + nf * 16 + col;
      float bb0 = b0[o], bb1 = b1[o];
      float s = 0.f;
#pragma unroll
      for (int mf = 0; mf < 2; ++mf)
#pragma unroll
        for (int j = 0; j < 4; ++j) {
          int row = mf * 16 + rb + j;
          if (row < valid)
            s += fmaxf(acc[mf][nf][j] + bb0 + degs_s[row] * bb1, 0.f);
        }
      s += __shfl_xor(s, 16);
      s += __shfl_xor(s, 32);
      if (lane < 16) atomicAdd(&pooled[batch * 256 + o], s * (1.0f / (float)kV));
    }
  } else {
    unsigned short* xn = (unsigned short*)out;
#pragma unroll
    for (int nf = 0; nf < 4; ++nf) {
      int o = obase + nf * 16 + col;
      float bb0 = b0[o], bb1 = b1[o];
#pragma unroll
      for (int mf = 0; mf < 2; ++mf)
#pragma unroll
        for (int j = 0; j < 4; ++j) {
          int row = mf * 16 + rb + j;
          float val = fmaxf(acc[mf][nf][j] + bb0 + degs_s[row] * bb1, 0.f);
          xn[(size_t)(v0 + row) * 256 + o] = f2b(val);
        }
    }
  }
}

// ---------------- MLP head ----------------

__global__ __launch_bounds__(256) void fc1_kernel(const float* __restrict__ pooled,
                                                  const float* __restrict__ w,
                                                  const float* __restrict__ b,
                                                  float* __restrict__ h) {
  __shared__ float ps[256];
  const int bb = blockIdx.x;
  const int o = blockIdx.y * 256 + threadIdx.x;
  ps[threadIdx.x] = pooled[bb * 256 + threadIdx.x];
  __syncthreads();
  const float4* wr = reinterpret_cast<const float4*>(w + (size_t)o * 256);
  float acc = b[o];
  for (int d4 = 0; d4 < 64; ++d4) {
    float4 wv = wr[d4];
    acc += ps[d4 * 4 + 0] * wv.x + ps[d4 * 4 + 1] * wv.y
         + ps[d4 * 4 + 2] * wv.z + ps[d4 * 4 + 3] * wv.w;
  }
  h[bb * 1024 + o] = fmaxf(acc, 0.f);
}

__global__ __launch_bounds__(256) void fc2_kernel(const float* __restrict__ h,
                                                  const float* __restrict__ w,
                                                  const float* __restrict__ b,
                                                  float* __restrict__ out) {
  const int t = threadIdx.x;
  if (t >= kB * 10) return;
  const int bb = t / 10, c = t % 10;
  const float* hr = h + bb * 1024;
  const float* wr = w + c * 1024;
  float acc = b[c];
  for (int k = 0; k < 1024; ++k) acc += hr[k] * wr[k];
  out[t] = acc;
}

}  // namespace

extern "C" void kernel_launch(void* const* d_in, const int* in_sizes, int n_in,
                              void* d_out, int out_size, void* d_ws, size_t ws_size,
                              hipStream_t stream) {
  const float* verts = (const float*)d_in[0];
  const int2*  edges = (const int2*)d_in[1];
  const float* g0w0 = (const float*)d_in[2];
  const float* g0b0 = (const float*)d_in[3];
  const float* g0w1 = (const float*)d_in[4];
  const float* g0b1 = (const float*)d_in[5];
  const float* g1w0 = (const float*)d_in[6];
  const float* g1b0 = (const float*)d_in[7];
  const float* g1w1 = (const float*)d_in[8];
  const float* g1b1 = (const float*)d_in[9];
  const float* g2w0 = (const float*)d_in[10];
  const float* g2b0 = (const float*)d_in[11];
  const float* g2w1 = (const float*)d_in[12];
  const float* g2b1 = (const float*)d_in[13];
  const float* fc1w = (const float*)d_in[14];
  const float* fc1b = (const float*)d_in[15];
  const float* fc2w = (const float*)d_in[16];
  const float* fc2b = (const float*)d_in[17];
  float* outp = (float*)d_out;

  char* p = (char*)d_ws;
  auto alloc = [&](size_t bytes) {
    char* r = p;
    p += (bytes + 255) & ~(size_t)255;
    return r;
  };
  unsigned short* x1   = (unsigned short*)alloc((size_t)kNV * 128 * 2);  // 39 MB bf16
  unsigned short* x2   = (unsigned short*)alloc((size_t)kNV * 256 * 2);  // 78 MB bf16
  unsigned short* wc1  = (unsigned short*)alloc((size_t)256 * 256 * 2);
  unsigned short* wc2  = (unsigned short*)alloc((size_t)256 * 512 * 2);
  int*   deg    = (int*)alloc((size_t)kNV * sizeof(int));
  int*   rowptr = (int*)alloc((size_t)(kNV + 1) * sizeof(int));
  int*   cursor = (int*)alloc((size_t)kNV * sizeof(int));
  int*   adj    = (int*)alloc((size_t)2 * kNE * sizeof(int));
  float* pooled = (float*)alloc((size_t)kB * 256 * sizeof(float));
  float* h      = (float*)alloc((size_t)kB * 1024 * sizeof(float));

  hipMemsetAsync(deg, 0, (size_t)kNV * sizeof(int), stream);
  hipMemsetAsync(pooled, 0, (size_t)kB * 256 * sizeof(float), stream);

  // CSR build
  count_deg_kernel<<<(kNE + 255) / 256, 256, 0, stream>>>(edges, deg);
  scan_kernel<<<1, 1024, 0, stream>>>(deg, rowptr, cursor);
  fill_adj_kernel<<<(kNE + 255) / 256, 256, 0, stream>>>(edges, cursor, adj);

  // Weight concat+cast (cheap, once per call)
  prep_wcat_kernel<<<256, 256, 0, stream>>>(g1w0, g1w1, wc1, 128);
  prep_wcat_kernel<<<256, 256, 0, stream>>>(g2w0, g2w1, wc2, 256);

  // GCN layers
  gcn_layer0_kernel<<<kNV / 32, 256, 0, stream>>>(verts, rowptr, adj,
                                                  g0w0, g0b0, g0w1, g0b1, x1);
  gcn_mfma_kernel<128, false><<<kNV / 32, 256, 0, stream>>>(
      x1, rowptr, adj, wc1, g1b0, g1b1, x2);
  gcn_mfma_kernel<256, true><<<dim3((kV + 31) / 32, kB), 256, 0, stream>>>(
      x2, rowptr, adj, wc2, g2b0, g2b1, pooled);

  // MLP head
  fc1_kernel<<<dim3(kB, 4), 256, 0, stream>>>(pooled, fc1w, fc1b, h);
  fc2_kernel<<<1, 256, 0, stream>>>(h, fc2w, fc2b, outp);
}

// Round 3
// 605.115 us; speedup vs baseline: 4.2756x; 1.5849x over previous
//
#include <hip/hip_runtime.h>
#include <hip/hip_bf16.h>

typedef __attribute__((ext_vector_type(8))) short short8;
typedef __attribute__((ext_vector_type(4))) float f32x4;

namespace {

constexpr int kNV = 160000;
constexpr int kNE = 480000;
constexpr int kB  = 16;
constexpr int kV  = 10000;
constexpr int kScanBlocks = kNV / 256;  // 625, exact

__device__ inline unsigned short f2b(float f) {  // fp32 -> bf16 RNE
  unsigned u = __float_as_uint(f);
  unsigned r = u + 0x7fffu + ((u >> 16) & 1u);
  return (unsigned short)(r >> 16);
}
__device__ inline float blo(unsigned u) { return __uint_as_float(u << 16); }
__device__ inline float bhi(unsigned u) { return __uint_as_float(u & 0xffff0000u); }

// ---------------- CSR build ----------------

__global__ __launch_bounds__(256) void count_deg_kernel(const int2* __restrict__ edges,
                                                        int* __restrict__ deg) {
  int i = blockIdx.x * 256 + threadIdx.x;
  if (i < kNE) {
    int2 e = edges[i];
    atomicAdd(&deg[e.x], 1);
    atomicAdd(&deg[e.y], 1);
  }
}

// Pass 1: per-block (256 elems) sums. kNV == 625*256 exactly, no tail.
__global__ __launch_bounds__(256) void block_sum_kernel(const int* __restrict__ deg,
                                                        int* __restrict__ bsum) {
  const int tid = threadIdx.x;
  int v = deg[blockIdx.x * 256 + tid];
  for (int off = 32; off > 0; off >>= 1) v += __shfl_down(v, off);
  __shared__ int ws[4];
  if ((tid & 63) == 0) ws[tid >> 6] = v;
  __syncthreads();
  if (tid == 0) bsum[blockIdx.x] = ws[0] + ws[1] + ws[2] + ws[3];
}

// Pass 2: scan the 625 block sums in one block; emit exclusive offsets + total.
__global__ __launch_bounds__(1024) void scan_bsum_kernel(const int* __restrict__ bsum,
                                                         int* __restrict__ boff,
                                                         int* __restrict__ total_out) {
  __shared__ int s[1024];
  const int t = threadIdx.x;
  int v = (t < kScanBlocks) ? bsum[t] : 0;
  s[t] = v;
  __syncthreads();
  for (int off = 1; off < 1024; off <<= 1) {
    int u = (t >= off) ? s[t - off] : 0;
    __syncthreads();
    s[t] += u;
    __syncthreads();
  }
  if (t < kScanBlocks) boff[t] = s[t] - v;
  if (t == kScanBlocks - 1) total_out[0] = s[t];
}

// Pass 3: intra-block exclusive scan + block offset -> rowptr & cursor.
__global__ __launch_bounds__(256) void write_rowptr_kernel(const int* __restrict__ deg,
                                                           const int* __restrict__ boff,
                                                           int* __restrict__ rowptr,
                                                           int* __restrict__ cursor) {
  __shared__ int s[256];
  const int tid = threadIdx.x;
  const int i = blockIdx.x * 256 + tid;
  int v = deg[i];
  s[tid] = v;
  __syncthreads();
  for (int off = 1; off < 256; off <<= 1) {
    int u = (tid >= off) ? s[tid - off] : 0;
    __syncthreads();
    s[tid] += u;
    __syncthreads();
  }
  int excl = s[tid] - v + boff[blockIdx.x];
  rowptr[i] = excl;
  cursor[i] = excl;
}

__global__ __launch_bounds__(256) void fill_adj_kernel(const int2* __restrict__ edges,
                                                       int* __restrict__ cursor,
                                                       int* __restrict__ adj) {
  int i = blockIdx.x * 256 + threadIdx.x;
  if (i < kNE) {
    int2 e = edges[i];
    int p = atomicAdd(&cursor[e.x], 1);
    adj[p] = e.y;
    int q = atomicAdd(&cursor[e.y], 1);
    adj[q] = e.x;
  }
}

// ---------------- Weight prep: Wcat[o][k] = [w0[o][:] | w1[o][:]] in bf16 ----

__global__ __launch_bounds__(256) void prep_wcat_kernel(const float* __restrict__ w0,
                                                        const float* __restrict__ w1,
                                                        unsigned short* __restrict__ wcat,
                                                        int din) {
  const int o = blockIdx.x;
  const int K = 2 * din;
  for (int k = threadIdx.x; k < din; k += 256) {
    wcat[(size_t)o * K + k]       = f2b(w0[(size_t)o * din + k]);
    wcat[(size_t)o * K + din + k] = f2b(w1[(size_t)o * din + k]);
  }
}

// ---------------- Layer 0: din=3 -> dout=128, bf16 output ----------------

__global__ __launch_bounds__(256) void gcn_layer0_kernel(
    const float* __restrict__ x, const int* __restrict__ rowptr,
    const int* __restrict__ adj, const float* __restrict__ w0,
    const float* __restrict__ b0, const float* __restrict__ w1,
    const float* __restrict__ b1, unsigned short* __restrict__ y) {
  constexpr int TM = 32, DOUT = 128;
  __shared__ float xs[TM][3];
  __shared__ float ags[TM][3];
  __shared__ float degs[TM];
  const int v0 = blockIdx.x * TM;
  const int tid = threadIdx.x;
  if (tid < TM * 3) xs[tid / 3][tid % 3] = x[(size_t)v0 * 3 + tid];
  if (tid < TM) {
    int v = v0 + tid;
    int beg = rowptr[v], end = rowptr[v + 1];
    float a0 = 0.f, a1 = 0.f, a2 = 0.f;
    for (int j = beg; j < end; ++j) {
      int u = adj[j];
      a0 += x[(size_t)u * 3 + 0];
      a1 += x[(size_t)u * 3 + 1];
      a2 += x[(size_t)u * 3 + 2];
    }
    ags[tid][0] = a0;
    ags[tid][1] = a1;
    ags[tid][2] = a2;
    degs[tid] = (float)(end - beg);
  }
  __syncthreads();
  const int o = tid & 127;
  const int half = tid >> 7;
  const float w00 = w0[o * 3], w01 = w0[o * 3 + 1], w02 = w0[o * 3 + 2];
  const float w10 = w1[o * 3], w11 = w1[o * 3 + 1], w12 = w1[o * 3 + 2];
  const float bb0 = b0[o], bb1 = b1[o];
  for (int m = half; m < TM; m += 2) {
    float r = bb0 + degs[m] * bb1
            + xs[m][0] * w00 + xs[m][1] * w01 + xs[m][2] * w02
            + ags[m][0] * w10 + ags[m][1] * w11 + ags[m][2] * w12;
    y[(size_t)(v0 + m) * DOUT + o] = f2b(fmaxf(r, 0.f));
  }
}

// ---------------- Fused GCN layer via MFMA (bf16) ----------------
// LDS tile: TM rows of [ x[v] (DIN bf16) | agg[v] (DIN bf16) ], K = 2*DIN.
// out[v] = relu( tile[v] @ Wcat.T + b0 + deg(v)*b1 );  POOL: mean-pool per batch.

template <int DIN, bool POOL>
__global__ __launch_bounds__(256) void gcn_mfma_kernel(
    const unsigned short* __restrict__ x, const int* __restrict__ rowptr,
    const int* __restrict__ adj, const unsigned short* __restrict__ wcat,
    const float* __restrict__ b0, const float* __restrict__ b1,
    void* __restrict__ out) {
  constexpr int TM = 32;
  constexpr int K = 2 * DIN;
  constexpr int ROWB = K * 2;  // bytes per LDS row
  __shared__ __align__(16) char lds[TM * ROWB];
  __shared__ float degs_s[TM];

  const int tid = threadIdx.x;
  const int lane = tid & 63;
  const int wave = tid >> 6;

  int v0, valid, batch;
  if constexpr (POOL) {
    batch = blockIdx.y;
    v0 = batch * kV + blockIdx.x * TM;
    valid = min(TM, kV - (int)blockIdx.x * TM);
  } else {
    batch = 0;
    v0 = blockIdx.x * TM;
    valid = TM;
  }

  auto swz = [&](int row, int off) { return row * ROWB + (off ^ ((row & 7) << 4)); };

  // ---- stage self rows (zero-fill rows beyond `valid`) ----
  constexpr int SLOTS = ROWB / 16;
  constexpr int SELF_SLOTS = (DIN * 2) / 16;
  for (int c = tid; c < TM * SLOTS; c += 256) {
    int row = c / SLOTS, slot = c % SLOTS;
    if (slot < SELF_SLOTS) {
      uint4 val;
      if (row < valid)
        val = *(const uint4*)(x + (size_t)(v0 + row) * DIN + slot * 8);
      else
        val = make_uint4(0, 0, 0, 0);
      *(uint4*)(lds + swz(row, slot * 16)) = val;
    } else if (row >= valid) {
      *(uint4*)(lds + swz(row, slot * 16)) = make_uint4(0, 0, 0, 0);
    }
  }

  // ---- neighbor aggregation: wave w owns vertices [w*8, w*8+8) ----
  const char* xb = (const char*)x;
  for (int mi = 0; mi < TM / 4; ++mi) {
    int m = wave * (TM / 4) + mi;
    if (m >= valid) break;
    int v = v0 + m;
    int beg = rowptr[v], end = rowptr[v + 1];
    if (lane == 0) degs_s[m] = (float)(end - beg);
    if constexpr (DIN == 128) {
      float r0 = 0.f, r1 = 0.f;
      int j = beg;
      for (; j + 4 <= end; j += 4) {
        int u0 = adj[j], u1 = adj[j + 1], u2 = adj[j + 2], u3 = adj[j + 3];
        unsigned a0 = *(const unsigned*)(xb + (size_t)u0 * 256 + lane * 4);
        unsigned a1 = *(const unsigned*)(xb + (size_t)u1 * 256 + lane * 4);
        unsigned a2 = *(const unsigned*)(xb + (size_t)u2 * 256 + lane * 4);
        unsigned a3 = *(const unsigned*)(xb + (size_t)u3 * 256 + lane * 4);
        r0 += blo(a0) + blo(a1) + blo(a2) + blo(a3);
        r1 += bhi(a0) + bhi(a1) + bhi(a2) + bhi(a3);
      }
      for (; j < end; ++j) {
        unsigned a = *(const unsigned*)(xb + (size_t)adj[j] * 256 + lane * 4);
        r0 += blo(a);
        r1 += bhi(a);
      }
      unsigned pk = ((unsigned)f2b(r1) << 16) | (unsigned)f2b(r0);
      *(unsigned*)(lds + swz(m, DIN * 2 + lane * 4)) = pk;
    } else {  // DIN == 256
      float r0 = 0.f, r1 = 0.f, r2 = 0.f, r3 = 0.f;
      int j = beg;
      for (; j + 4 <= end; j += 4) {
        int u0 = adj[j], u1 = adj[j + 1], u2 = adj[j + 2], u3 = adj[j + 3];
        uint2 a0 = *(const uint2*)(xb + (size_t)u0 * 512 + lane * 8);
        uint2 a1 = *(const uint2*)(xb + (size_t)u1 * 512 + lane * 8);
        uint2 a2 = *(const uint2*)(xb + (size_t)u2 * 512 + lane * 8);
        uint2 a3 = *(const uint2*)(xb + (size_t)u3 * 512 + lane * 8);
        r0 += blo(a0.x) + blo(a1.x) + blo(a2.x) + blo(a3.x);
        r1 += bhi(a0.x) + bhi(a1.x) + bhi(a2.x) + bhi(a3.x);
        r2 += blo(a0.y) + blo(a1.y) + blo(a2.y) + blo(a3.y);
        r3 += bhi(a0.y) + bhi(a1.y) + bhi(a2.y) + bhi(a3.y);
      }
      for (; j < end; ++j) {
        uint2 a = *(const uint2*)(xb + (size_t)adj[j] * 512 + lane * 8);
        r0 += blo(a.x);
        r1 += bhi(a.x);
        r2 += blo(a.y);
        r3 += bhi(a.y);
      }
      uint2 pk;
      pk.x = ((unsigned)f2b(r1) << 16) | (unsigned)f2b(r0);
      pk.y = ((unsigned)f2b(r3) << 16) | (unsigned)f2b(r2);
      *(uint2*)(lds + swz(m, DIN * 2 + lane * 8)) = pk;
    }
  }
  __syncthreads();

  // ---- MFMA transform: wave w computes channels [w*64, w*64+64), all 32 rows
  const int col = lane & 15;
  const int kgrp = lane >> 4;
  const int obase = wave * 64;
  f32x4 acc[2][4] = {};
  for (int k0 = 0; k0 < K; k0 += 32) {
    const int kb = (k0 + kgrp * 8) * 2;
    short8 a0 = *(const short8*)(lds + swz(col, kb));
    short8 a1 = *(const short8*)(lds + swz(col + 16, kb));
    const unsigned short* wp = wcat + (size_t)(obase + col) * K + k0 + kgrp * 8;
#pragma unroll
    for (int nf = 0; nf < 4; ++nf) {
      short8 bfrag = *(const short8*)(wp + (size_t)nf * 16 * K);
      acc[0][nf] = __builtin_amdgcn_mfma_f32_16x16x32_bf16(a0, bfrag, acc[0][nf], 0, 0, 0);
      acc[1][nf] = __builtin_amdgcn_mfma_f32_16x16x32_bf16(a1, bfrag, acc[1][nf], 0, 0, 0);
    }
  }

  // ---- epilogue: C/D map col=lane&15, row=(lane>>4)*4+reg (+16 for mf=1) ----
  const int rb = kgrp * 4;
  if constexpr (POOL) {
    float* pooled = (float*)out;
#pragma unroll
    for (int nf = 0; nf < 4; ++nf) {
      int o = obase + nf * 16 + col;
      float bb0 = b0[o], bb1 = b1[o];
      float s = 0.f;
#pragma unroll
      for (int mf = 0; mf < 2; ++mf)
#pragma unroll
        for (int j = 0; j < 4; ++j) {
          int row = mf * 16 + rb + j;
          if (row < valid)
            s += fmaxf(acc[mf][nf][j] + bb0 + degs_s[row] * bb1, 0.f);
        }
      s += __shfl_xor(s, 16);
      s += __shfl_xor(s, 32);
      if (lane < 16) atomicAdd(&pooled[batch * 256 + o], s * (1.0f / (float)kV));
    }
  } else {
    unsigned short* xn = (unsigned short*)out;
#pragma unroll
    for (int nf = 0; nf < 4; ++nf) {
      int o = obase + nf * 16 + col;
      float bb0 = b0[o], bb1 = b1[o];
#pragma unroll
      for (int mf = 0; mf < 2; ++mf)
#pragma unroll
        for (int j = 0; j < 4; ++j) {
          int row = mf * 16 + rb + j;
          float val = fmaxf(acc[mf][nf][j] + bb0 + degs_s[row] * bb1, 0.f);
          xn[(size_t)(v0 + row) * 256 + o] = f2b(val);
        }
    }
  }
}

// ---------------- MLP head ----------------

__global__ __launch_bounds__(256) void fc1_kernel(const float* __restrict__ pooled,
                                                  const float* __restrict__ w,
                                                  const float* __restrict__ b,
                                                  float* __restrict__ h) {
  __shared__ float ps[256];
  const int bb = blockIdx.x;
  const int o = blockIdx.y * 256 + threadIdx.x;
  ps[threadIdx.x] = pooled[bb * 256 + threadIdx.x];
  __syncthreads();
  const float4* wr = reinterpret_cast<const float4*>(w + (size_t)o * 256);
  float acc = b[o];
  for (int d4 = 0; d4 < 64; ++d4) {
    float4 wv = wr[d4];
    acc += ps[d4 * 4 + 0] * wv.x + ps[d4 * 4 + 1] * wv.y
         + ps[d4 * 4 + 2] * wv.z + ps[d4 * 4 + 3] * wv.w;
  }
  h[bb * 1024 + o] = fmaxf(acc, 0.f);
}

__global__ __launch_bounds__(256) void fc2_kernel(const float* __restrict__ h,
                                                  const float* __restrict__ w,
                                                  const float* __restrict__ b,
                                                  float* __restrict__ out) {
  const int t = threadIdx.x;
  if (t >= kB * 10) return;
  const int bb = t / 10, c = t % 10;
  const float* hr = h + bb * 1024;
  const float* wr = w + c * 1024;
  float acc = b[c];
  for (int k = 0; k < 1024; ++k) acc += hr[k] * wr[k];
  out[t] = acc;
}

}  // namespace

extern "C" void kernel_launch(void* const* d_in, const int* in_sizes, int n_in,
                              void* d_out, int out_size, void* d_ws, size_t ws_size,
                              hipStream_t stream) {
  const float* verts = (const float*)d_in[0];
  const int2*  edges = (const int2*)d_in[1];
  const float* g0w0 = (const float*)d_in[2];
  const float* g0b0 = (const float*)d_in[3];
  const float* g0w1 = (const float*)d_in[4];
  const float* g0b1 = (const float*)d_in[5];
  const float* g1w0 = (const float*)d_in[6];
  const float* g1b0 = (const float*)d_in[7];
  const float* g1w1 = (const float*)d_in[8];
  const float* g1b1 = (const float*)d_in[9];
  const float* g2w0 = (const float*)d_in[10];
  const float* g2b0 = (const float*)d_in[11];
  const float* g2w1 = (const float*)d_in[12];
  const float* g2b1 = (const float*)d_in[13];
  const float* fc1w = (const float*)d_in[14];
  const float* fc1b = (const float*)d_in[15];
  const float* fc2w = (const float*)d_in[16];
  const float* fc2b = (const float*)d_in[17];
  float* outp = (float*)d_out;

  char* p = (char*)d_ws;
  auto alloc = [&](size_t bytes) {
    char* r = p;
    p += (bytes + 255) & ~(size_t)255;
    return r;
  };
  unsigned short* x1   = (unsigned short*)alloc((size_t)kNV * 128 * 2);  // 39 MB bf16
  unsigned short* x2   = (unsigned short*)alloc((size_t)kNV * 256 * 2);  // 78 MB bf16
  unsigned short* wc1  = (unsigned short*)alloc((size_t)256 * 256 * 2);
  unsigned short* wc2  = (unsigned short*)alloc((size_t)256 * 512 * 2);
  int*   deg    = (int*)alloc((size_t)kNV * sizeof(int));
  int*   rowptr = (int*)alloc((size_t)(kNV + 1) * sizeof(int));
  int*   cursor = (int*)alloc((size_t)kNV * sizeof(int));
  int*   adj    = (int*)alloc((size_t)2 * kNE * sizeof(int));
  int*   bsum   = (int*)alloc((size_t)kScanBlocks * sizeof(int));
  int*   boff   = (int*)alloc((size_t)kScanBlocks * sizeof(int));
  float* pooled = (float*)alloc((size_t)kB * 256 * sizeof(float));
  float* h      = (float*)alloc((size_t)kB * 1024 * sizeof(float));

  hipMemsetAsync(deg, 0, (size_t)kNV * sizeof(int), stream);
  hipMemsetAsync(pooled, 0, (size_t)kB * 256 * sizeof(float), stream);

  // CSR build (parallel 3-pass scan; kNV = 625*256 exactly)
  count_deg_kernel<<<(kNE + 255) / 256, 256, 0, stream>>>(edges, deg);
  block_sum_kernel<<<kScanBlocks, 256, 0, stream>>>(deg, bsum);
  scan_bsum_kernel<<<1, 1024, 0, stream>>>(bsum, boff, rowptr + kNV);
  write_rowptr_kernel<<<kScanBlocks, 256, 0, stream>>>(deg, boff, rowptr, cursor);
  fill_adj_kernel<<<(kNE + 255) / 256, 256, 0, stream>>>(edges, cursor, adj);

  // Weight concat+cast (cheap, once per call)
  prep_wcat_kernel<<<256, 256, 0, stream>>>(g1w0, g1w1, wc1, 128);
  prep_wcat_kernel<<<256, 256, 0, stream>>>(g2w0, g2w1, wc2, 256);

  // GCN layers
  gcn_layer0_kernel<<<kNV / 32, 256, 0, stream>>>(verts, rowptr, adj,
                                                  g0w0, g0b0, g0w1, g0b1, x1);
  gcn_mfma_kernel<128, false><<<kNV / 32, 256, 0, stream>>>(
      x1, rowptr, adj, wc1, g1b0, g1b1, x2);
  gcn_mfma_kernel<256, true><<<dim3((kV + 31) / 32, kB), 256, 0, stream>>>(
      x2, rowptr, adj, wc2, g2b0, g2b1, pooled);

  // MLP head
  fc1_kernel<<<dim3(kB, 4), 256, 0, stream>>>(pooled, fc1w, fc1b, h);
  fc2_kernel<<<1, 256, 0, stream>>>(h, fc2w, fc2b, outp);
}

// Round 4
// 575.453 us; speedup vs baseline: 4.4960x; 1.0515x over previous
//
#include <hip/hip_runtime.h>
#include <hip/hip_bf16.h>

typedef __attribute__((ext_vector_type(8))) short short8;
typedef __attribute__((ext_vector_type(4))) float f32x4;

namespace {

constexpr int kNV = 160000;
constexpr int kNE = 480000;
constexpr int kB  = 16;
constexpr int kV  = 10000;
constexpr int kScanBlocks = kNV / 256;  // 625, exact
constexpr int kMaxAdjPad = 2 * kNE + 3 * kNV;  // 1,440,000 worst case

__device__ inline unsigned short f2b(float f) {  // fp32 -> bf16 RNE
  unsigned u = __float_as_uint(f);
  unsigned r = u + 0x7fffu + ((u >> 16) & 1u);
  return (unsigned short)(r >> 16);
}
__device__ inline float blo(unsigned u) { return __uint_as_float(u << 16); }
__device__ inline float bhi(unsigned u) { return __uint_as_float(u & 0xffff0000u); }

// ---------------- CSR build (degree-padded to multiples of 4) ----------------

__global__ __launch_bounds__(256) void count_deg_kernel(const int2* __restrict__ edges,
                                                        int* __restrict__ deg) {
  int i = blockIdx.x * 256 + threadIdx.x;
  if (i < kNE) {
    int2 e = edges[i];
    atomicAdd(&deg[e.x], 1);
    atomicAdd(&deg[e.y], 1);
  }
}

// Pass 1: per-block (256 elems) sums of PADDED degree.
__global__ __launch_bounds__(256) void block_sum_kernel(const int* __restrict__ deg,
                                                        int* __restrict__ bsum) {
  const int tid = threadIdx.x;
  int v = (deg[blockIdx.x * 256 + tid] + 3) & ~3;
  for (int off = 32; off > 0; off >>= 1) v += __shfl_down(v, off);
  __shared__ int ws[4];
  if ((tid & 63) == 0) ws[tid >> 6] = v;
  __syncthreads();
  if (tid == 0) bsum[blockIdx.x] = ws[0] + ws[1] + ws[2] + ws[3];
}

// Pass 2: scan the 625 block sums; exclusive offsets + total.
__global__ __launch_bounds__(1024) void scan_bsum_kernel(const int* __restrict__ bsum,
                                                         int* __restrict__ boff,
                                                         int* __restrict__ total_out) {
  __shared__ int s[1024];
  const int t = threadIdx.x;
  int v = (t < kScanBlocks) ? bsum[t] : 0;
  s[t] = v;
  __syncthreads();
  for (int off = 1; off < 1024; off <<= 1) {
    int u = (t >= off) ? s[t - off] : 0;
    __syncthreads();
    s[t] += u;
    __syncthreads();
  }
  if (t < kScanBlocks) boff[t] = s[t] - v;
  if (t == kScanBlocks - 1) total_out[0] = s[t];
}

// Pass 3: intra-block scan of padded degree + block offset -> rowptr & cursor.
__global__ __launch_bounds__(256) void write_rowptr_kernel(const int* __restrict__ deg,
                                                           const int* __restrict__ boff,
                                                           int* __restrict__ rowptr,
                                                           int* __restrict__ cursor) {
  __shared__ int s[256];
  const int tid = threadIdx.x;
  const int i = blockIdx.x * 256 + tid;
  int v = (deg[i] + 3) & ~3;
  s[tid] = v;
  __syncthreads();
  for (int off = 1; off < 256; off <<= 1) {
    int u = (tid >= off) ? s[tid - off] : 0;
    __syncthreads();
    s[tid] += u;
    __syncthreads();
  }
  int excl = s[tid] - v + boff[blockIdx.x];
  rowptr[i] = excl;
  cursor[i] = excl;
}

__global__ __launch_bounds__(256) void fill_adj_kernel(const int2* __restrict__ edges,
                                                       int* __restrict__ cursor,
                                                       int* __restrict__ adj) {
  int i = blockIdx.x * 256 + threadIdx.x;
  if (i < kNE) {
    int2 e = edges[i];
    int p = atomicAdd(&cursor[e.x], 1);
    adj[p] = e.y;
    int q = atomicAdd(&cursor[e.y], 1);
    adj[q] = e.x;
  }
}

// Fill pad slots [rowptr[v]+deg[v], rowptr[v+1]) with the zero-row index kNV.
__global__ __launch_bounds__(256) void pad_adj_kernel(const int* __restrict__ deg,
                                                      const int* __restrict__ rowptr,
                                                      int* __restrict__ adj) {
  int v = blockIdx.x * 256 + threadIdx.x;
  if (v < kNV) {
    int e = rowptr[v] + deg[v];
    int e2 = rowptr[v + 1];
    for (int p = e; p < e2; ++p) adj[p] = kNV;
  }
}

// ---------------- Weight prep: Wcat[o][k] = [w0[o][:] | w1[o][:]] in bf16 ----

__global__ __launch_bounds__(256) void prep_wcat_kernel(const float* __restrict__ w0,
                                                        const float* __restrict__ w1,
                                                        unsigned short* __restrict__ wcat,
                                                        int din) {
  const int o = blockIdx.x;
  const int K = 2 * din;
  for (int k = threadIdx.x; k < din; k += 256) {
    wcat[(size_t)o * K + k]       = f2b(w0[(size_t)o * din + k]);
    wcat[(size_t)o * K + din + k] = f2b(w1[(size_t)o * din + k]);
  }
}

// ---------------- Layer 0: din=3 -> dout=128, wave-parallel gather ----------

__global__ __launch_bounds__(256) void gcn_layer0_kernel(
    const float* __restrict__ x, const int* __restrict__ rowptr,
    const int* __restrict__ deg, const int* __restrict__ adj,
    const float* __restrict__ w0, const float* __restrict__ b0,
    const float* __restrict__ w1, const float* __restrict__ b1,
    unsigned short* __restrict__ y) {
  constexpr int TM = 32, DOUT = 128;
  __shared__ float xs[TM][3];
  __shared__ float ags[TM][3];
  __shared__ float degs[TM];
  const int v0 = blockIdx.x * TM;
  const int tid = threadIdx.x;
  const int lane = tid & 63;
  const int wave = tid >> 6;
  if (tid < TM * 3) xs[tid / 3][tid % 3] = x[(size_t)v0 * 3 + tid];

  // wave w gathers rows [w*8, w*8+8): lanes cover neighbors in parallel.
  for (int mi = 0; mi < 8; ++mi) {
    int m = wave * 8 + mi;
    int v = v0 + m;
    int beg = rowptr[v];
    int n = deg[v];  // real degree; pad entries not touched (verts has no pad row)
    float a0 = 0.f, a1 = 0.f, a2 = 0.f;
    for (int c = 0; c < n; c += 64) {
      int l = c + lane;
      if (l < n) {
        int u = adj[beg + l];
        a0 += x[(size_t)u * 3 + 0];
        a1 += x[(size_t)u * 3 + 1];
        a2 += x[(size_t)u * 3 + 2];
      }
    }
#pragma unroll
    for (int off = 32; off > 0; off >>= 1) {
      a0 += __shfl_xor(a0, off);
      a1 += __shfl_xor(a1, off);
      a2 += __shfl_xor(a2, off);
    }
    if (lane == 0) {
      ags[m][0] = a0;
      ags[m][1] = a1;
      ags[m][2] = a2;
      degs[m] = (float)n;
    }
  }
  __syncthreads();

  const int o = tid & 127;
  const int half = tid >> 7;
  const float w00 = w0[o * 3], w01 = w0[o * 3 + 1], w02 = w0[o * 3 + 2];
  const float w10 = w1[o * 3], w11 = w1[o * 3 + 1], w12 = w1[o * 3 + 2];
  const float bb0 = b0[o], bb1 = b1[o];
  for (int m = half; m < TM; m += 2) {
    float r = bb0 + degs[m] * bb1
            + xs[m][0] * w00 + xs[m][1] * w01 + xs[m][2] * w02
            + ags[m][0] * w10 + ags[m][1] * w11 + ags[m][2] * w12;
    y[(size_t)(v0 + m) * DOUT + o] = f2b(fmaxf(r, 0.f));
  }
}

// ---------------- Fused GCN layer via MFMA (bf16) ----------------
// LDS holds ONLY the aggregate tile (TM rows x DIN bf16, swizzled).
// MFMA pass 0: self rows (A-frags straight from global x), W0 half of wcat.
// MFMA pass 1: agg rows from LDS, W1 half of wcat.
// Gather: padded CSR (deg multiple of 4, pads -> zero row kNV), 2-deep pipeline.

template <int DIN, bool POOL>
__global__ __launch_bounds__(256, 5) void gcn_mfma_kernel(
    const unsigned short* __restrict__ x, const int* __restrict__ rowptr,
    const int* __restrict__ deg, const int* __restrict__ adj,
    const unsigned short* __restrict__ wcat,
    const float* __restrict__ b0, const float* __restrict__ b1,
    void* __restrict__ out) {
  constexpr int TM = 32;
  constexpr int K = 2 * DIN;
  constexpr int ROWB = DIN * 2;  // bytes per LDS agg row
  __shared__ __align__(16) char lds[TM * ROWB];
  __shared__ float degs_s[TM];

  const int tid = threadIdx.x;
  const int lane = tid & 63;
  const int wave = tid >> 6;

  int v0, valid, batch;
  if constexpr (POOL) {
    batch = blockIdx.y;
    v0 = batch * kV + blockIdx.x * TM;
    valid = min(TM, kV - (int)blockIdx.x * TM);
  } else {
    batch = 0;
    v0 = blockIdx.x * TM;
    valid = TM;
  }

  auto swz = [&](int row, int off) { return row * ROWB + (off ^ ((row & 7) << 4)); };

  const int4* adjq = reinterpret_cast<const int4*>(adj);

  // ---- gather: wave w owns rows [w*8, w*8+8) ----
  for (int mi = 0; mi < 8; ++mi) {
    int m = wave * 8 + mi;
    bool live = m < valid;
    int v = live ? (v0 + m) : v0;
    int beg = rowptr[v];
    int nq = live ? ((rowptr[v + 1] - beg) >> 2) : 0;  // padded degree / 4
    int n = live ? deg[v] : 0;
    if (lane == 0) degs_s[m] = (float)n;
    const int q0 = beg >> 2;

    if constexpr (DIN == 256) {
      const uint2* xr = reinterpret_cast<const uint2*>(x);  // row = 64 uint2
      float r0 = 0.f, r1 = 0.f, r2 = 0.f, r3 = 0.f;
      if (nq > 0) {
        int4 iB;
        int4 iA = adjq[q0];
        if (nq > 1) iB = adjq[q0 + 1];
        uint2 c0 = xr[(size_t)iA.x * 64 + lane];
        uint2 c1 = xr[(size_t)iA.y * 64 + lane];
        uint2 c2 = xr[(size_t)iA.z * 64 + lane];
        uint2 c3 = xr[(size_t)iA.w * 64 + lane];
        for (int t = 1; t < nq; ++t) {
          uint2 n0 = xr[(size_t)iB.x * 64 + lane];
          uint2 n1 = xr[(size_t)iB.y * 64 + lane];
          uint2 n2 = xr[(size_t)iB.z * 64 + lane];
          uint2 n3 = xr[(size_t)iB.w * 64 + lane];
          if (t + 1 < nq) iB = adjq[q0 + t + 1];
          r0 += blo(c0.x) + blo(c1.x) + blo(c2.x) + blo(c3.x);
          r1 += bhi(c0.x) + bhi(c1.x) + bhi(c2.x) + bhi(c3.x);
          r2 += blo(c0.y) + blo(c1.y) + blo(c2.y) + blo(c3.y);
          r3 += bhi(c0.y) + bhi(c1.y) + bhi(c2.y) + bhi(c3.y);
          c0 = n0; c1 = n1; c2 = n2; c3 = n3;
        }
        r0 += blo(c0.x) + blo(c1.x) + blo(c2.x) + blo(c3.x);
        r1 += bhi(c0.x) + bhi(c1.x) + bhi(c2.x) + bhi(c3.x);
        r2 += blo(c0.y) + blo(c1.y) + blo(c2.y) + blo(c3.y);
        r3 += bhi(c0.y) + bhi(c1.y) + bhi(c2.y) + bhi(c3.y);
      }
      uint2 pk;
      pk.x = ((unsigned)f2b(r1) << 16) | (unsigned)f2b(r0);
      pk.y = ((unsigned)f2b(r3) << 16) | (unsigned)f2b(r2);
      *(uint2*)(lds + swz(m, lane * 8)) = pk;
    } else {  // DIN == 128
      const unsigned* xr = reinterpret_cast<const unsigned*>(x);  // row = 64 uints
      float r0 = 0.f, r1 = 0.f;
      if (nq > 0) {
        int4 iB;
        int4 iA = adjq[q0];
        if (nq > 1) iB = adjq[q0 + 1];
        unsigned c0 = xr[(size_t)iA.x * 64 + lane];
        unsigned c1 = xr[(size_t)iA.y * 64 + lane];
        unsigned c2 = xr[(size_t)iA.z * 64 + lane];
        unsigned c3 = xr[(size_t)iA.w * 64 + lane];
        for (int t = 1; t < nq; ++t) {
          unsigned n0 = xr[(size_t)iB.x * 64 + lane];
          unsigned n1 = xr[(size_t)iB.y * 64 + lane];
          unsigned n2 = xr[(size_t)iB.z * 64 + lane];
          unsigned n3 = xr[(size_t)iB.w * 64 + lane];
          if (t + 1 < nq) iB = adjq[q0 + t + 1];
          r0 += blo(c0) + blo(c1) + blo(c2) + blo(c3);
          r1 += bhi(c0) + bhi(c1) + bhi(c2) + bhi(c3);
          c0 = n0; c1 = n1; c2 = n2; c3 = n3;
        }
        r0 += blo(c0) + blo(c1) + blo(c2) + blo(c3);
        r1 += bhi(c0) + bhi(c1) + bhi(c2) + bhi(c3);
      }
      unsigned pk = ((unsigned)f2b(r1) << 16) | (unsigned)f2b(r0);
      *(unsigned*)(lds + swz(m, lane * 4)) = pk;
    }
  }
  __syncthreads();

  // ---- MFMA transform: wave w -> channels [w*64, w*64+64) ----
  const int col = lane & 15;
  const int kgrp = lane >> 4;
  const int obase = wave * 64;
  f32x4 acc[2][4] = {};

  // pass 0: self rows from global, W0 half
  for (int k0 = 0; k0 < DIN; k0 += 32) {
    const int ke = k0 + kgrp * 8;
    short8 a0 = {}, a1 = {};
    if constexpr (POOL) {
      if (col < valid)      a0 = *(const short8*)(x + (size_t)(v0 + col) * DIN + ke);
      if (col + 16 < valid) a1 = *(const short8*)(x + (size_t)(v0 + col + 16) * DIN + ke);
    } else {
      a0 = *(const short8*)(x + (size_t)(v0 + col) * DIN + ke);
      a1 = *(const short8*)(x + (size_t)(v0 + col + 16) * DIN + ke);
    }
    const unsigned short* wp = wcat + (size_t)(obase + col) * K + ke;
#pragma unroll
    for (int nf = 0; nf < 4; ++nf) {
      short8 bfrag = *(const short8*)(wp + (size_t)nf * 16 * K);
      acc[0][nf] = __builtin_amdgcn_mfma_f32_16x16x32_bf16(a0, bfrag, acc[0][nf], 0, 0, 0);
      acc[1][nf] = __builtin_amdgcn_mfma_f32_16x16x32_bf16(a1, bfrag, acc[1][nf], 0, 0, 0);
    }
  }
  // pass 1: agg rows from LDS, W1 half
  for (int k0 = 0; k0 < DIN; k0 += 32) {
    const int kb = (k0 + kgrp * 8) * 2;
    short8 a0 = *(const short8*)(lds + swz(col, kb));
    short8 a1 = *(const short8*)(lds + swz(col + 16, kb));
    const unsigned short* wp = wcat + (size_t)(obase + col) * K + DIN + k0 + kgrp * 8;
#pragma unroll
    for (int nf = 0; nf < 4; ++nf) {
      short8 bfrag = *(const short8*)(wp + (size_t)nf * 16 * K);
      acc[0][nf] = __builtin_amdgcn_mfma_f32_16x16x32_bf16(a0, bfrag, acc[0][nf], 0, 0, 0);
      acc[1][nf] = __builtin_amdgcn_mfma_f32_16x16x32_bf16(a1, bfrag, acc[1][nf], 0, 0, 0);
    }
  }

  // ---- epilogue: C/D map col=lane&15, row=(lane>>4)*4+reg (+16 for mf=1) ----
  const int rb = kgrp * 4;
  if constexpr (POOL) {
    float* part = (float*)out;  // [kB][16][256] partial slots
    const int slot = blockIdx.x & 15;
#pragma unroll
    for (int nf = 0; nf < 4; ++nf) {
      int o = obase + nf * 16 + col;
      float bb0 = b0[o], bb1 = b1[o];
      float s = 0.f;
#pragma unroll
      for (int mf = 0; mf < 2; ++mf)
#pragma unroll
        for (int j = 0; j < 4; ++j) {
          int row = mf * 16 + rb + j;
          if (row < valid)
            s += fmaxf(acc[mf][nf][j] + bb0 + degs_s[row] * bb1, 0.f);
        }
      s += __shfl_xor(s, 16);
      s += __shfl_xor(s, 32);
      if (lane < 16)
        atomicAdd(&part[((size_t)batch * 16 + slot) * 256 + o], s * (1.0f / (float)kV));
    }
  } else {
    unsigned short* xn = (unsigned short*)out;
#pragma unroll
    for (int nf = 0; nf < 4; ++nf) {
      int o = obase + nf * 16 + col;
      float bb0 = b0[o], bb1 = b1[o];
#pragma unroll
      for (int mf = 0; mf < 2; ++mf)
#pragma unroll
        for (int j = 0; j < 4; ++j) {
          int row = mf * 16 + rb + j;
          float val = fmaxf(acc[mf][nf][j] + bb0 + degs_s[row] * bb1, 0.f);
          xn[(size_t)(v0 + row) * 256 + o] = f2b(val);
        }
    }
  }
}

// Sum the 16 partial slots per batch into pooled[b][o].
__global__ __launch_bounds__(256) void pool_reduce_kernel(const float* __restrict__ part,
                                                          float* __restrict__ pooled) {
  const int b = blockIdx.x;
  const int o = threadIdx.x;
  float s = 0.f;
#pragma unroll
  for (int k = 0; k < 16; ++k) s += part[((size_t)b * 16 + k) * 256 + o];
  pooled[b * 256 + o] = s;
}

// ---------------- MLP head ----------------

__global__ __launch_bounds__(256) void fc1_kernel(const float* __restrict__ pooled,
                                                  const float* __restrict__ w,
                                                  const float* __restrict__ b,
                                                  float* __restrict__ h) {
  __shared__ float ps[256];
  const int bb = blockIdx.x;
  const int o = blockIdx.y * 256 + threadIdx.x;
  ps[threadIdx.x] = pooled[bb * 256 + threadIdx.x];
  __syncthreads();
  const float4* wr = reinterpret_cast<const float4*>(w + (size_t)o * 256);
  float acc = b[o];
  for (int d4 = 0; d4 < 64; ++d4) {
    float4 wv = wr[d4];
    acc += ps[d4 * 4 + 0] * wv.x + ps[d4 * 4 + 1] * wv.y
         + ps[d4 * 4 + 2] * wv.z + ps[d4 * 4 + 3] * wv.w;
  }
  h[bb * 1024 + o] = fmaxf(acc, 0.f);
}

// One wave per output element: lanes stride the K=1024 dot product.
__global__ __launch_bounds__(64) void fc2_kernel(const float* __restrict__ h,
                                                 const float* __restrict__ w,
                                                 const float* __restrict__ b,
                                                 float* __restrict__ out) {
  const int t = blockIdx.x;  // 0..159
  const int bb = t / 10, c = t % 10;
  const int lane = threadIdx.x;
  const float* hr = h + bb * 1024;
  const float* wr = w + c * 1024;
  float acc = 0.f;
#pragma unroll
  for (int k = 0; k < 16; ++k) acc += hr[k * 64 + lane] * wr[k * 64 + lane];
#pragma unroll
  for (int off = 32; off > 0; off >>= 1) acc += __shfl_xor(acc, off);
  if (lane == 0) out[t] = acc + b[c];
}

}  // namespace

extern "C" void kernel_launch(void* const* d_in, const int* in_sizes, int n_in,
                              void* d_out, int out_size, void* d_ws, size_t ws_size,
                              hipStream_t stream) {
  const float* verts = (const float*)d_in[0];
  const int2*  edges = (const int2*)d_in[1];
  const float* g0w0 = (const float*)d_in[2];
  const float* g0b0 = (const float*)d_in[3];
  const float* g0w1 = (const float*)d_in[4];
  const float* g0b1 = (const float*)d_in[5];
  const float* g1w0 = (const float*)d_in[6];
  const float* g1b0 = (const float*)d_in[7];
  const float* g1w1 = (const float*)d_in[8];
  const float* g1b1 = (const float*)d_in[9];
  const float* g2w0 = (const float*)d_in[10];
  const float* g2b0 = (const float*)d_in[11];
  const float* g2w1 = (const float*)d_in[12];
  const float* g2b1 = (const float*)d_in[13];
  const float* fc1w = (const float*)d_in[14];
  const float* fc1b = (const float*)d_in[15];
  const float* fc2w = (const float*)d_in[16];
  const float* fc2b = (const float*)d_in[17];
  float* outp = (float*)d_out;

  char* p = (char*)d_ws;
  auto alloc = [&](size_t bytes) {
    char* r = p;
    p += (bytes + 255) & ~(size_t)255;
    return r;
  };
  unsigned short* x1   = (unsigned short*)alloc((size_t)(kNV + 1) * 128 * 2);  // +zero row
  unsigned short* x2   = (unsigned short*)alloc((size_t)(kNV + 1) * 256 * 2);  // +zero row
  unsigned short* wc1  = (unsigned short*)alloc((size_t)256 * 256 * 2);
  unsigned short* wc2  = (unsigned short*)alloc((size_t)256 * 512 * 2);
  int*   deg    = (int*)alloc((size_t)kNV * sizeof(int));
  int*   rowptr = (int*)alloc((size_t)(kNV + 1) * sizeof(int));
  int*   cursor = (int*)alloc((size_t)kNV * sizeof(int));
  int*   adj    = (int*)alloc((size_t)kMaxAdjPad * sizeof(int));
  int*   bsum   = (int*)alloc((size_t)kScanBlocks * sizeof(int));
  int*   boff   = (int*)alloc((size_t)kScanBlocks * sizeof(int));
  float* part   = (float*)alloc((size_t)kB * 16 * 256 * sizeof(float));
  float* pooled = (float*)alloc((size_t)kB * 256 * sizeof(float));
  float* h      = (float*)alloc((size_t)kB * 1024 * sizeof(float));

  hipMemsetAsync(deg, 0, (size_t)kNV * sizeof(int), stream);
  hipMemsetAsync(part, 0, (size_t)kB * 16 * 256 * sizeof(float), stream);
  hipMemsetAsync(x1 + (size_t)kNV * 128, 0, 128 * 2, stream);  // zero row
  hipMemsetAsync(x2 + (size_t)kNV * 256, 0, 256 * 2, stream);  // zero row

  // CSR build, degree-padded to multiples of 4
  count_deg_kernel<<<(kNE + 255) / 256, 256, 0, stream>>>(edges, deg);
  block_sum_kernel<<<kScanBlocks, 256, 0, stream>>>(deg, bsum);
  scan_bsum_kernel<<<1, 1024, 0, stream>>>(bsum, boff, rowptr + kNV);
  write_rowptr_kernel<<<kScanBlocks, 256, 0, stream>>>(deg, boff, rowptr, cursor);
  fill_adj_kernel<<<(kNE + 255) / 256, 256, 0, stream>>>(edges, cursor, adj);
  pad_adj_kernel<<<(kNV + 255) / 256, 256, 0, stream>>>(deg, rowptr, adj);

  // Weight concat+cast
  prep_wcat_kernel<<<256, 256, 0, stream>>>(g1w0, g1w1, wc1, 128);
  prep_wcat_kernel<<<256, 256, 0, stream>>>(g2w0, g2w1, wc2, 256);

  // GCN layers
  gcn_layer0_kernel<<<kNV / 32, 256, 0, stream>>>(verts, rowptr, deg, adj,
                                                  g0w0, g0b0, g0w1, g0b1, x1);
  gcn_mfma_kernel<128, false><<<kNV / 32, 256, 0, stream>>>(
      x1, rowptr, deg, adj, wc1, g1b0, g1b1, x2);
  gcn_mfma_kernel<256, true><<<dim3((kV + 31) / 32, kB), 256, 0, stream>>>(
      x2, rowptr, deg, adj, wc2, g2b0, g2b1, part);
  pool_reduce_kernel<<<kB, 256, 0, stream>>>(part, pooled);

  // MLP head
  fc1_kernel<<<dim3(kB, 4), 256, 0, stream>>>(pooled, fc1w, fc1b, h);
  fc2_kernel<<<kB * 10, 64, 0, stream>>>(h, fc2w, fc2b, outp);
}

// Round 5
// 481.117 us; speedup vs baseline: 5.3775x; 1.1961x over previous
//
#include <hip/hip_runtime.h>
#include <hip/hip_bf16.h>

typedef __attribute__((ext_vector_type(8))) short short8;
typedef __attribute__((ext_vector_type(4))) float f32x4;

namespace {

constexpr int kNV = 160000;
constexpr int kNE = 480000;
constexpr int kB  = 16;
constexpr int kV  = 10000;
constexpr int kScanBlocks = kNV / 256;  // 625, exact
constexpr int kMaxAdjPad = 2 * kNE + 3 * kNV;  // 1,440,000 worst case

__device__ inline unsigned short f2b(float f) {  // fp32 -> bf16 RNE
  unsigned u = __float_as_uint(f);
  unsigned r = u + 0x7fffu + ((u >> 16) & 1u);
  return (unsigned short)(r >> 16);
}
__device__ inline float blo(unsigned u) { return __uint_as_float(u << 16); }
__device__ inline float bhi(unsigned u) { return __uint_as_float(u & 0xffff0000u); }
__device__ inline unsigned pk2(float lo, float hi) {
  return ((unsigned)f2b(hi) << 16) | (unsigned)f2b(lo);
}

// ---------------- CSR build (degree-padded to multiples of 4) ----------------

__global__ __launch_bounds__(256) void count_deg_kernel(const int2* __restrict__ edges,
                                                        int* __restrict__ deg) {
  int i = blockIdx.x * 256 + threadIdx.x;
  if (i < kNE) {
    int2 e = edges[i];
    atomicAdd(&deg[e.x], 1);
    atomicAdd(&deg[e.y], 1);
  }
}

__global__ __launch_bounds__(256) void block_sum_kernel(const int* __restrict__ deg,
                                                        int* __restrict__ bsum) {
  const int tid = threadIdx.x;
  int v = (deg[blockIdx.x * 256 + tid] + 3) & ~3;
  for (int off = 32; off > 0; off >>= 1) v += __shfl_down(v, off);
  __shared__ int ws[4];
  if ((tid & 63) == 0) ws[tid >> 6] = v;
  __syncthreads();
  if (tid == 0) bsum[blockIdx.x] = ws[0] + ws[1] + ws[2] + ws[3];
}

__global__ __launch_bounds__(1024) void scan_bsum_kernel(const int* __restrict__ bsum,
                                                         int* __restrict__ boff,
                                                         int* __restrict__ total_out) {
  __shared__ int s[1024];
  const int t = threadIdx.x;
  int v = (t < kScanBlocks) ? bsum[t] : 0;
  s[t] = v;
  __syncthreads();
  for (int off = 1; off < 1024; off <<= 1) {
    int u = (t >= off) ? s[t - off] : 0;
    __syncthreads();
    s[t] += u;
    __syncthreads();
  }
  if (t < kScanBlocks) boff[t] = s[t] - v;
  if (t == kScanBlocks - 1) total_out[0] = s[t];
}

__global__ __launch_bounds__(256) void write_rowptr_kernel(const int* __restrict__ deg,
                                                           const int* __restrict__ boff,
                                                           int* __restrict__ rowptr,
                                                           int* __restrict__ cursor) {
  __shared__ int s[256];
  const int tid = threadIdx.x;
  const int i = blockIdx.x * 256 + tid;
  int v = (deg[i] + 3) & ~3;
  s[tid] = v;
  __syncthreads();
  for (int off = 1; off < 256; off <<= 1) {
    int u = (tid >= off) ? s[tid - off] : 0;
    __syncthreads();
    s[tid] += u;
    __syncthreads();
  }
  int excl = s[tid] - v + boff[blockIdx.x];
  rowptr[i] = excl;
  cursor[i] = excl;
}

__global__ __launch_bounds__(256) void fill_adj_kernel(const int2* __restrict__ edges,
                                                       int* __restrict__ cursor,
                                                       int* __restrict__ adj) {
  int i = blockIdx.x * 256 + threadIdx.x;
  if (i < kNE) {
    int2 e = edges[i];
    int p = atomicAdd(&cursor[e.x], 1);
    adj[p] = e.y;
    int q = atomicAdd(&cursor[e.y], 1);
    adj[q] = e.x;
  }
}

__global__ __launch_bounds__(256) void pad_adj_kernel(const int* __restrict__ deg,
                                                      const int* __restrict__ rowptr,
                                                      int* __restrict__ adj) {
  int v = blockIdx.x * 256 + threadIdx.x;
  if (v < kNV) {
    int e = rowptr[v] + deg[v];
    int e2 = rowptr[v + 1];
    for (int p = e; p < e2; ++p) adj[p] = kNV;
  }
}

// ------- Weight prep: MFMA-fragment-swizzled concat [W0|W1] in bf16 --------
// dst group g (16 B / short8) at byte g*16; g = (s*16 + cb)*64 + lane.
// lane -> (col = lane&15, kgrp = lane>>4); value[j] = Wcat[ch][k] with
// ch = cb*16+col, k = s*32 + kgrp*8 + j. A wave's B-frag load is then a
// fully contiguous 1 KB: wswz + ((s*16+cb)*64 + lane)*8.

__global__ __launch_bounds__(256) void prep_wswz_kernel(const float* __restrict__ w0,
                                                        const float* __restrict__ w1,
                                                        unsigned short* __restrict__ dst,
                                                        int din) {
  const int K = 2 * din;
  const int total = (K / 32) * 16 * 64;
  int g = blockIdx.x * 256 + threadIdx.x;
  if (g >= total) return;
  int lane = g & 63;
  int cb = (g >> 6) & 15;
  int s = g >> 10;
  int ch = cb * 16 + (lane & 15);
  int kb = s * 32 + (lane >> 4) * 8;
  unsigned short v[8];
#pragma unroll
  for (int j = 0; j < 8; ++j) {
    int k = kb + j;
    float f = (k < din) ? w0[(size_t)ch * din + k] : w1[(size_t)ch * din + (k - din)];
    v[j] = f2b(f);
  }
  uint4 pk;
  pk.x = (unsigned)v[0] | ((unsigned)v[1] << 16);
  pk.y = (unsigned)v[2] | ((unsigned)v[3] << 16);
  pk.z = (unsigned)v[4] | ((unsigned)v[5] << 16);
  pk.w = (unsigned)v[6] | ((unsigned)v[7] << 16);
  *(uint4*)(dst + (size_t)g * 8) = pk;
}

// ---------------- Layer 0: din=3 -> dout=128, wave-parallel gather ----------

__global__ __launch_bounds__(256) void gcn_layer0_kernel(
    const float* __restrict__ x, const int* __restrict__ rowptr,
    const int* __restrict__ deg, const int* __restrict__ adj,
    const float* __restrict__ w0, const float* __restrict__ b0,
    const float* __restrict__ w1, const float* __restrict__ b1,
    unsigned short* __restrict__ y) {
  constexpr int TM = 32, DOUT = 128;
  __shared__ float xs[TM][3];
  __shared__ float ags[TM][3];
  __shared__ float degs[TM];
  const int v0 = blockIdx.x * TM;
  const int tid = threadIdx.x;
  const int lane = tid & 63;
  const int wave = tid >> 6;
  if (tid < TM * 3) xs[tid / 3][tid % 3] = x[(size_t)v0 * 3 + tid];

  for (int mi = 0; mi < 8; ++mi) {
    int m = wave * 8 + mi;
    int v = v0 + m;
    int beg = rowptr[v];
    int n = deg[v];
    float a0 = 0.f, a1 = 0.f, a2 = 0.f;
    for (int c = 0; c < n; c += 64) {
      int l = c + lane;
      if (l < n) {
        int u = adj[beg + l];
        a0 += x[(size_t)u * 3 + 0];
        a1 += x[(size_t)u * 3 + 1];
        a2 += x[(size_t)u * 3 + 2];
      }
    }
#pragma unroll
    for (int off = 32; off > 0; off >>= 1) {
      a0 += __shfl_xor(a0, off);
      a1 += __shfl_xor(a1, off);
      a2 += __shfl_xor(a2, off);
    }
    if (lane == 0) {
      ags[m][0] = a0;
      ags[m][1] = a1;
      ags[m][2] = a2;
      degs[m] = (float)n;
    }
  }
  __syncthreads();

  const int o = tid & 127;
  const int half = tid >> 7;
  const float w00 = w0[o * 3], w01 = w0[o * 3 + 1], w02 = w0[o * 3 + 2];
  const float w10 = w1[o * 3], w11 = w1[o * 3 + 1], w12 = w1[o * 3 + 2];
  const float bb0 = b0[o], bb1 = b1[o];
  for (int m = half; m < TM; m += 2) {
    float r = bb0 + degs[m] * bb1
            + xs[m][0] * w00 + xs[m][1] * w01 + xs[m][2] * w02
            + ags[m][0] * w10 + ags[m][1] * w11 + ags[m][2] * w12;
    y[(size_t)(v0 + m) * DOUT + o] = f2b(fmaxf(r, 0.f));
  }
}

// ---------------- Fused GCN layer via MFMA (bf16) ----------------
// Gather: dual-row half-wave (2 rows/instruction, 8 row-loads in flight).
// Pass 0 (self rows from global, W0 half) runs BEFORE the barrier so gather
// stragglers overlap with MFMA. Pass 1 (agg from LDS, W1 half) after barrier.
// Weights come pre-swizzled (prep_wswz_kernel) -> contiguous 1 KB B-frag loads.

template <int DIN, bool POOL>
__global__ __launch_bounds__(256, 6) void gcn_mfma_kernel(
    const unsigned short* __restrict__ x, const int* __restrict__ rowptr,
    const int* __restrict__ deg, const int* __restrict__ adj,
    const unsigned short* __restrict__ wswz,
    const float* __restrict__ b0, const float* __restrict__ b1,
    void* __restrict__ out) {
  constexpr int TM = 32;
  constexpr int ROWB = DIN * 2;  // bytes per LDS agg row
  __shared__ __align__(16) char lds[TM * ROWB];
  __shared__ float degs_s[TM];

  const int tid = threadIdx.x;
  const int lane = tid & 63;
  const int wave = tid >> 6;
  const int half = lane >> 5;  // row-pair selector
  const int hl = lane & 31;    // position within row

  int v0, valid, batch;
  if constexpr (POOL) {
    batch = blockIdx.y;
    v0 = batch * kV + blockIdx.x * TM;
    valid = min(TM, kV - (int)blockIdx.x * TM);
  } else {
    batch = 0;
    v0 = blockIdx.x * TM;
    valid = TM;
  }

  auto swz = [&](int row, int off) { return row * ROWB + (off ^ ((row & 7) << 4)); };

  const int4* adjq = reinterpret_cast<const int4*>(adj);
  const int4 Z4 = make_int4(kNV, kNV, kNV, kNV);

  // ---- gather: wave owns rows [wave*8, wave*8+8) as 4 dual-row pairs ----
  for (int pr = 0; pr < 4; ++pr) {
    const int m = wave * 8 + pr * 2 + half;
    const bool live = m < valid;
    const int v = live ? (v0 + m) : v0;
    const int beg = rowptr[v];
    const int nq = live ? ((rowptr[v + 1] - beg) >> 2) : 0;
    if (hl == 0) degs_s[m] = live ? (float)deg[v] : 0.f;
    const int nqo = __shfl_xor(nq, 32);
    const int nqmax = max(nq, nqo);
    const int q0 = beg >> 2;

    if constexpr (DIN == 256) {
      const uint4* xr = reinterpret_cast<const uint4*>(x);  // row = 32 uint4
      float r0 = 0, r1 = 0, r2 = 0, r3 = 0, r4 = 0, r5 = 0, r6 = 0, r7 = 0;
#define ACC8(c) do { r0 += blo((c).x); r1 += bhi((c).x); r2 += blo((c).y); \
                     r3 += bhi((c).y); r4 += blo((c).z); r5 += bhi((c).z); \
                     r6 += blo((c).w); r7 += bhi((c).w); } while (0)
      if (nqmax > 0) {
        int4 iq = (0 < nq) ? adjq[q0] : Z4;
        uint4 c0 = xr[(size_t)iq.x * 32 + hl];
        uint4 c1 = xr[(size_t)iq.y * 32 + hl];
        uint4 c2 = xr[(size_t)iq.z * 32 + hl];
        uint4 c3 = xr[(size_t)iq.w * 32 + hl];
        for (int t = 1; t < nqmax; ++t) {
          int4 jq = (t < nq) ? adjq[q0 + t] : Z4;
          uint4 n0 = xr[(size_t)jq.x * 32 + hl];
          uint4 n1 = xr[(size_t)jq.y * 32 + hl];
          uint4 n2 = xr[(size_t)jq.z * 32 + hl];
          uint4 n3 = xr[(size_t)jq.w * 32 + hl];
          ACC8(c0); ACC8(c1); ACC8(c2); ACC8(c3);
          c0 = n0; c1 = n1; c2 = n2; c3 = n3;
        }
        ACC8(c0); ACC8(c1); ACC8(c2); ACC8(c3);
      }
#undef ACC8
      uint4 pk;
      pk.x = pk2(r0, r1);
      pk.y = pk2(r2, r3);
      pk.z = pk2(r4, r5);
      pk.w = pk2(r6, r7);
      *(uint4*)(lds + swz(m, hl * 16)) = pk;
    } else {  // DIN == 128
      const uint2* xr = reinterpret_cast<const uint2*>(x);  // row = 32 uint2
      float r0 = 0, r1 = 0, r2 = 0, r3 = 0;
#define ACC4(c) do { r0 += blo((c).x); r1 += bhi((c).x); \
                     r2 += blo((c).y); r3 += bhi((c).y); } while (0)
      if (nqmax > 0) {
        int4 iq = (0 < nq) ? adjq[q0] : Z4;
        uint2 c0 = xr[(size_t)iq.x * 32 + hl];
        uint2 c1 = xr[(size_t)iq.y * 32 + hl];
        uint2 c2 = xr[(size_t)iq.z * 32 + hl];
        uint2 c3 = xr[(size_t)iq.w * 32 + hl];
        for (int t = 1; t < nqmax; ++t) {
          int4 jq = (t < nq) ? adjq[q0 + t] : Z4;
          uint2 n0 = xr[(size_t)jq.x * 32 + hl];
          uint2 n1 = xr[(size_t)jq.y * 32 + hl];
          uint2 n2 = xr[(size_t)jq.z * 32 + hl];
          uint2 n3 = xr[(size_t)jq.w * 32 + hl];
          ACC4(c0); ACC4(c1); ACC4(c2); ACC4(c3);
          c0 = n0; c1 = n1; c2 = n2; c3 = n3;
        }
        ACC4(c0); ACC4(c1); ACC4(c2); ACC4(c3);
      }
#undef ACC4
      uint2 pk;
      pk.x = pk2(r0, r1);
      pk.y = pk2(r2, r3);
      *(uint2*)(lds + swz(m, hl * 8)) = pk;
    }
  }

  // ---- MFMA: wave -> channels [wave*64, wave*64+64) ----
  const int col = lane & 15;
  const int kgrp = lane >> 4;
  const int cbw = wave * 4;  // channel-block base (16-ch blocks)
  f32x4 acc[2][4] = {};

  // pass 0: self rows straight from global, W0 half (s in [0, DIN/32))
  for (int s = 0; s < DIN / 32; ++s) {
    const int ke = s * 32 + kgrp * 8;
    short8 a0 = {}, a1 = {};
    if constexpr (POOL) {
      if (col < valid)      a0 = *(const short8*)(x + (size_t)(v0 + col) * DIN + ke);
      if (col + 16 < valid) a1 = *(const short8*)(x + (size_t)(v0 + col + 16) * DIN + ke);
    } else {
      a0 = *(const short8*)(x + (size_t)(v0 + col) * DIN + ke);
      a1 = *(const short8*)(x + (size_t)(v0 + col + 16) * DIN + ke);
    }
    const unsigned short* wb = wswz + ((size_t)(s * 16 + cbw) * 64 + lane) * 8;
#pragma unroll
    for (int nf = 0; nf < 4; ++nf) {
      short8 bfrag = *(const short8*)(wb + (size_t)nf * 512);
      acc[0][nf] = __builtin_amdgcn_mfma_f32_16x16x32_bf16(a0, bfrag, acc[0][nf], 0, 0, 0);
      acc[1][nf] = __builtin_amdgcn_mfma_f32_16x16x32_bf16(a1, bfrag, acc[1][nf], 0, 0, 0);
    }
  }

  __syncthreads();

  // pass 1: agg rows from LDS, W1 half (s in [DIN/32, 2*DIN/32))
  for (int s2 = 0; s2 < DIN / 32; ++s2) {
    const int kb = (s2 * 32 + kgrp * 8) * 2;
    short8 a0 = *(const short8*)(lds + swz(col, kb));
    short8 a1 = *(const short8*)(lds + swz(col + 16, kb));
    const unsigned short* wb =
        wswz + ((size_t)((DIN / 32 + s2) * 16 + cbw) * 64 + lane) * 8;
#pragma unroll
    for (int nf = 0; nf < 4; ++nf) {
      short8 bfrag = *(const short8*)(wb + (size_t)nf * 512);
      acc[0][nf] = __builtin_amdgcn_mfma_f32_16x16x32_bf16(a0, bfrag, acc[0][nf], 0, 0, 0);
      acc[1][nf] = __builtin_amdgcn_mfma_f32_16x16x32_bf16(a1, bfrag, acc[1][nf], 0, 0, 0);
    }
  }

  // ---- epilogue: C/D map col=lane&15, row=(lane>>4)*4+reg (+16 for mf=1) ----
  const int rb = kgrp * 4;
  const int obase = wave * 64;
  if constexpr (POOL) {
    float* part = (float*)out;  // [kB][16][256] partial slots
    const int slot = blockIdx.x & 15;
#pragma unroll
    for (int nf = 0; nf < 4; ++nf) {
      int o = obase + nf * 16 + col;
      float bb0 = b0[o], bb1 = b1[o];
      float s = 0.f;
#pragma unroll
      for (int mf = 0; mf < 2; ++mf)
#pragma unroll
        for (int j = 0; j < 4; ++j) {
          int row = mf * 16 + rb + j;
          if (row < valid)
            s += fmaxf(acc[mf][nf][j] + bb0 + degs_s[row] * bb1, 0.f);
        }
      s += __shfl_xor(s, 16);
      s += __shfl_xor(s, 32);
      if (lane < 16)
        atomicAdd(&part[((size_t)batch * 16 + slot) * 256 + o], s * (1.0f / (float)kV));
    }
  } else {
    unsigned short* xn = (unsigned short*)out;
#pragma unroll
    for (int nf = 0; nf < 4; ++nf) {
      int o = obase + nf * 16 + col;
      float bb0 = b0[o], bb1 = b1[o];
#pragma unroll
      for (int mf = 0; mf < 2; ++mf)
#pragma unroll
        for (int j = 0; j < 4; ++j) {
          int row = mf * 16 + rb + j;
          float val = fmaxf(acc[mf][nf][j] + bb0 + degs_s[row] * bb1, 0.f);
          xn[(size_t)(v0 + row) * 256 + o] = f2b(val);
        }
    }
  }
}

// Sum the 16 partial slots per batch into pooled[b][o].
__global__ __launch_bounds__(256) void pool_reduce_kernel(const float* __restrict__ part,
                                                          float* __restrict__ pooled) {
  const int b = blockIdx.x;
  const int o = threadIdx.x;
  float s = 0.f;
#pragma unroll
  for (int k = 0; k < 16; ++k) s += part[((size_t)b * 16 + k) * 256 + o];
  pooled[b * 256 + o] = s;
}

// ---------------- MLP head ----------------

__global__ __launch_bounds__(256) void fc1_kernel(const float* __restrict__ pooled,
                                                  const float* __restrict__ w,
                                                  const float* __restrict__ b,
                                                  float* __restrict__ h) {
  __shared__ float ps[256];
  const int bb = blockIdx.x;
  const int o = blockIdx.y * 256 + threadIdx.x;
  ps[threadIdx.x] = pooled[bb * 256 + threadIdx.x];
  __syncthreads();
  const float4* wr = reinterpret_cast<const float4*>(w + (size_t)o * 256);
  float acc = b[o];
  for (int d4 = 0; d4 < 64; ++d4) {
    float4 wv = wr[d4];
    acc += ps[d4 * 4 + 0] * wv.x + ps[d4 * 4 + 1] * wv.y
         + ps[d4 * 4 + 2] * wv.z + ps[d4 * 4 + 3] * wv.w;
  }
  h[bb * 1024 + o] = fmaxf(acc, 0.f);
}

__global__ __launch_bounds__(64) void fc2_kernel(const float* __restrict__ h,
                                                 const float* __restrict__ w,
                                                 const float* __restrict__ b,
                                                 float* __restrict__ out) {
  const int t = blockIdx.x;  // 0..159
  const int bb = t / 10, c = t % 10;
  const int lane = threadIdx.x;
  const float* hr = h + bb * 1024;
  const float* wr = w + c * 1024;
  float acc = 0.f;
#pragma unroll
  for (int k = 0; k < 16; ++k) acc += hr[k * 64 + lane] * wr[k * 64 + lane];
#pragma unroll
  for (int off = 32; off > 0; off >>= 1) acc += __shfl_xor(acc, off);
  if (lane == 0) out[t] = acc + b[c];
}

}  // namespace

extern "C" void kernel_launch(void* const* d_in, const int* in_sizes, int n_in,
                              void* d_out, int out_size, void* d_ws, size_t ws_size,
                              hipStream_t stream) {
  const float* verts = (const float*)d_in[0];
  const int2*  edges = (const int2*)d_in[1];
  const float* g0w0 = (const float*)d_in[2];
  const float* g0b0 = (const float*)d_in[3];
  const float* g0w1 = (const float*)d_in[4];
  const float* g0b1 = (const float*)d_in[5];
  const float* g1w0 = (const float*)d_in[6];
  const float* g1b0 = (const float*)d_in[7];
  const float* g1w1 = (const float*)d_in[8];
  const float* g1b1 = (const float*)d_in[9];
  const float* g2w0 = (const float*)d_in[10];
  const float* g2b0 = (const float*)d_in[11];
  const float* g2w1 = (const float*)d_in[12];
  const float* g2b1 = (const float*)d_in[13];
  const float* fc1w = (const float*)d_in[14];
  const float* fc1b = (const float*)d_in[15];
  const float* fc2w = (const float*)d_in[16];
  const float* fc2b = (const float*)d_in[17];
  float* outp = (float*)d_out;

  char* p = (char*)d_ws;
  auto alloc = [&](size_t bytes) {
    char* r = p;
    p += (bytes + 255) & ~(size_t)255;
    return r;
  };
  unsigned short* x1   = (unsigned short*)alloc((size_t)(kNV + 1) * 128 * 2);  // +zero row
  unsigned short* x2   = (unsigned short*)alloc((size_t)(kNV + 1) * 256 * 2);  // +zero row
  unsigned short* ws1  = (unsigned short*)alloc((size_t)256 * 256 * 2);  // swizzled [W0|W1]
  unsigned short* ws2  = (unsigned short*)alloc((size_t)256 * 512 * 2);
  int*   deg    = (int*)alloc((size_t)kNV * sizeof(int));
  int*   rowptr = (int*)alloc((size_t)(kNV + 1) * sizeof(int));
  int*   cursor = (int*)alloc((size_t)kNV * sizeof(int));
  int*   adj    = (int*)alloc((size_t)kMaxAdjPad * sizeof(int));
  int*   bsum   = (int*)alloc((size_t)kScanBlocks * sizeof(int));
  int*   boff   = (int*)alloc((size_t)kScanBlocks * sizeof(int));
  float* part   = (float*)alloc((size_t)kB * 16 * 256 * sizeof(float));
  float* pooled = (float*)alloc((size_t)kB * 256 * sizeof(float));
  float* h      = (float*)alloc((size_t)kB * 1024 * sizeof(float));

  hipMemsetAsync(deg, 0, (size_t)kNV * sizeof(int), stream);
  hipMemsetAsync(part, 0, (size_t)kB * 16 * 256 * sizeof(float), stream);
  hipMemsetAsync(x1 + (size_t)kNV * 128, 0, 128 * 2, stream);  // zero row
  hipMemsetAsync(x2 + (size_t)kNV * 256, 0, 256 * 2, stream);  // zero row

  // CSR build, degree-padded to multiples of 4
  count_deg_kernel<<<(kNE + 255) / 256, 256, 0, stream>>>(edges, deg);
  block_sum_kernel<<<kScanBlocks, 256, 0, stream>>>(deg, bsum);
  scan_bsum_kernel<<<1, 1024, 0, stream>>>(bsum, boff, rowptr + kNV);
  write_rowptr_kernel<<<kScanBlocks, 256, 0, stream>>>(deg, boff, rowptr, cursor);
  fill_adj_kernel<<<(kNE + 255) / 256, 256, 0, stream>>>(edges, cursor, adj);
  pad_adj_kernel<<<(kNV + 255) / 256, 256, 0, stream>>>(deg, rowptr, adj);

  // Weight cast + MFMA-fragment swizzle
  prep_wswz_kernel<<<32, 256, 0, stream>>>(g1w0, g1w1, ws1, 128);
  prep_wswz_kernel<<<64, 256, 0, stream>>>(g2w0, g2w1, ws2, 256);

  // GCN layers
  gcn_layer0_kernel<<<kNV / 32, 256, 0, stream>>>(verts, rowptr, deg, adj,
                                                  g0w0, g0b0, g0w1, g0b1, x1);
  gcn_mfma_kernel<128, false><<<kNV / 32, 256, 0, stream>>>(
      x1, rowptr, deg, adj, ws1, g1b0, g1b1, x2);
  gcn_mfma_kernel<256, true><<<dim3((kV + 31) / 32, kB), 256, 0, stream>>>(
      x2, rowptr, deg, adj, ws2, g2b0, g2b1, part);
  pool_reduce_kernel<<<kB, 256, 0, stream>>>(part, pooled);

  // MLP head
  fc1_kernel<<<dim3(kB, 4), 256, 0, stream>>>(pooled, fc1w, fc1b, h);
  fc2_kernel<<<kB * 10, 64, 0, stream>>>(h, fc2w, fc2b, outp);
}

// Round 6
// 461.212 us; speedup vs baseline: 5.6096x; 1.0432x over previous
//
#include <hip/hip_runtime.h>
#include <hip/hip_bf16.h>

typedef __attribute__((ext_vector_type(8))) short short8;
typedef __attribute__((ext_vector_type(4))) float f32x4;

namespace {

constexpr int kNV = 160000;
constexpr int kNE = 480000;
constexpr int kB  = 16;
constexpr int kV  = 10000;
constexpr int kScanBlocks = kNV / 256;  // 625, exact
constexpr int kMaxAdjPad = 2 * kNE + 3 * kNV;  // 1,440,000 worst case

__device__ inline unsigned short f2b(float f) {  // fp32 -> bf16 RNE
  unsigned u = __float_as_uint(f);
  unsigned r = u + 0x7fffu + ((u >> 16) & 1u);
  return (unsigned short)(r >> 16);
}
__device__ inline float blo(unsigned u) { return __uint_as_float(u << 16); }
__device__ inline float bhi(unsigned u) { return __uint_as_float(u & 0xffff0000u); }
__device__ inline unsigned pk2(float lo, float hi) {
  return ((unsigned)f2b(hi) << 16) | (unsigned)f2b(lo);
}

// ---------------- CSR build (degree-padded to multiples of 4) ----------------

__global__ __launch_bounds__(256) void count_deg_kernel(const int2* __restrict__ edges,
                                                        int* __restrict__ deg) {
  int i = blockIdx.x * 256 + threadIdx.x;
  if (i < kNE) {
    int2 e = edges[i];
    atomicAdd(&deg[e.x], 1);
    atomicAdd(&deg[e.y], 1);
  }
}

__global__ __launch_bounds__(256) void block_sum_kernel(const int* __restrict__ deg,
                                                        int* __restrict__ bsum) {
  const int tid = threadIdx.x;
  int v = (deg[blockIdx.x * 256 + tid] + 3) & ~3;
  for (int off = 32; off > 0; off >>= 1) v += __shfl_down(v, off);
  __shared__ int ws[4];
  if ((tid & 63) == 0) ws[tid >> 6] = v;
  __syncthreads();
  if (tid == 0) bsum[blockIdx.x] = ws[0] + ws[1] + ws[2] + ws[3];
}

__global__ __launch_bounds__(1024) void scan_bsum_kernel(const int* __restrict__ bsum,
                                                         int* __restrict__ boff,
                                                         int* __restrict__ total_out) {
  __shared__ int s[1024];
  const int t = threadIdx.x;
  int v = (t < kScanBlocks) ? bsum[t] : 0;
  s[t] = v;
  __syncthreads();
  for (int off = 1; off < 1024; off <<= 1) {
    int u = (t >= off) ? s[t - off] : 0;
    __syncthreads();
    s[t] += u;
    __syncthreads();
  }
  if (t < kScanBlocks) boff[t] = s[t] - v;
  if (t == kScanBlocks - 1) total_out[0] = s[t];
}

__global__ __launch_bounds__(256) void write_rowptr_kernel(const int* __restrict__ deg,
                                                           const int* __restrict__ boff,
                                                           int* __restrict__ rowptr,
                                                           int* __restrict__ cursor) {
  __shared__ int s[256];
  const int tid = threadIdx.x;
  const int i = blockIdx.x * 256 + tid;
  int v = (deg[i] + 3) & ~3;
  s[tid] = v;
  __syncthreads();
  for (int off = 1; off < 256; off <<= 1) {
    int u = (tid >= off) ? s[tid - off] : 0;
    __syncthreads();
    s[tid] += u;
    __syncthreads();
  }
  int excl = s[tid] - v + boff[blockIdx.x];
  rowptr[i] = excl;
  cursor[i] = excl;
}

__global__ __launch_bounds__(256) void fill_adj_kernel(const int2* __restrict__ edges,
                                                       int* __restrict__ cursor,
                                                       int* __restrict__ adj) {
  int i = blockIdx.x * 256 + threadIdx.x;
  if (i < kNE) {
    int2 e = edges[i];
    int p = atomicAdd(&cursor[e.x], 1);
    adj[p] = e.y;
    int q = atomicAdd(&cursor[e.y], 1);
    adj[q] = e.x;
  }
}

__global__ __launch_bounds__(256) void pad_adj_kernel(const int* __restrict__ deg,
                                                      const int* __restrict__ rowptr,
                                                      int* __restrict__ adj) {
  int v = blockIdx.x * 256 + threadIdx.x;
  if (v < kNV) {
    int e = rowptr[v] + deg[v];
    int e2 = rowptr[v + 1];
    for (int p = e; p < e2; ++p) adj[p] = kNV;
  }
}

// ------- Weight prep: MFMA-fragment-swizzled concat [W0|W1] in bf16 --------
// dst group g (16 B / short8) at byte g*16; g = (s*16 + cb)*64 + lane.
// lane -> (col = lane&15, kgrp = lane>>4); value[j] = Wcat[ch][k] with
// ch = cb*16+col, k = s*32 + kgrp*8 + j. A wave's B-frag load is then a
// fully contiguous 1 KB: wswz + ((s*16+cb)*64 + lane)*8.

__global__ __launch_bounds__(256) void prep_wswz_kernel(const float* __restrict__ w0,
                                                        const float* __restrict__ w1,
                                                        unsigned short* __restrict__ dst,
                                                        int din) {
  const int K = 2 * din;
  const int total = (K / 32) * 16 * 64;
  int g = blockIdx.x * 256 + threadIdx.x;
  if (g >= total) return;
  int lane = g & 63;
  int cb = (g >> 6) & 15;
  int s = g >> 10;
  int ch = cb * 16 + (lane & 15);
  int kb = s * 32 + (lane >> 4) * 8;
  unsigned short v[8];
#pragma unroll
  for (int j = 0; j < 8; ++j) {
    int k = kb + j;
    float f = (k < din) ? w0[(size_t)ch * din + k] : w1[(size_t)ch * din + (k - din)];
    v[j] = f2b(f);
  }
  uint4 pk;
  pk.x = (unsigned)v[0] | ((unsigned)v[1] << 16);
  pk.y = (unsigned)v[2] | ((unsigned)v[3] << 16);
  pk.z = (unsigned)v[4] | ((unsigned)v[5] << 16);
  pk.w = (unsigned)v[6] | ((unsigned)v[7] << 16);
  *(uint4*)(dst + (size_t)g * 8) = pk;
}

// ------ Layer 0: din=3 -> dout=128, thread-per-vertex gather (L2-resident) --

__global__ __launch_bounds__(256) void gcn_layer0_kernel(
    const float* __restrict__ x, const int* __restrict__ rowptr,
    const int* __restrict__ deg, const int* __restrict__ adj,
    const float* __restrict__ w0, const float* __restrict__ b0,
    const float* __restrict__ w1, const float* __restrict__ b1,
    unsigned short* __restrict__ y) {
  constexpr int TM = 256, DOUT = 128;
  __shared__ __align__(16) float xa[TM][8];  // [0..2] self, [3..5] agg, [6] deg
  const int v0 = blockIdx.x * TM;
  const int tid = threadIdx.x;

  // phase 1: self + gather, one thread per vertex (verts is ~1.9 MB: L2-hot)
  {
    const int v = v0 + tid;
    const float s0 = x[(size_t)v * 3 + 0];
    const float s1 = x[(size_t)v * 3 + 1];
    const float s2 = x[(size_t)v * 3 + 2];
    const int beg = rowptr[v];
    const int n = deg[v];  // real degree (pad entries excluded)
    float a0 = 0.f, a1 = 0.f, a2 = 0.f;
    int j = beg;
    const int e = beg + n;
    for (; j + 4 <= e; j += 4) {
      int u0 = adj[j], u1 = adj[j + 1], u2 = adj[j + 2], u3 = adj[j + 3];
      float p0 = x[(size_t)u0 * 3], p1 = x[(size_t)u0 * 3 + 1], p2 = x[(size_t)u0 * 3 + 2];
      float q0 = x[(size_t)u1 * 3], q1 = x[(size_t)u1 * 3 + 1], q2 = x[(size_t)u1 * 3 + 2];
      float r0 = x[(size_t)u2 * 3], r1 = x[(size_t)u2 * 3 + 1], r2 = x[(size_t)u2 * 3 + 2];
      float t0 = x[(size_t)u3 * 3], t1 = x[(size_t)u3 * 3 + 1], t2 = x[(size_t)u3 * 3 + 2];
      a0 += (p0 + q0) + (r0 + t0);
      a1 += (p1 + q1) + (r1 + t1);
      a2 += (p2 + q2) + (r2 + t2);
    }
    for (; j < e; ++j) {
      int u = adj[j];
      a0 += x[(size_t)u * 3 + 0];
      a1 += x[(size_t)u * 3 + 1];
      a2 += x[(size_t)u * 3 + 2];
    }
    xa[tid][0] = s0;
    xa[tid][1] = s1;
    xa[tid][2] = s2;
    xa[tid][3] = a0;
    xa[tid][4] = a1;
    xa[tid][5] = a2;
    xa[tid][6] = (float)n;
    xa[tid][7] = 0.f;
  }
  __syncthreads();

  // phase 2: channel-per-thread transform; xa rows read as 2x float4 broadcast
  const int o = tid & 127;
  const int half = tid >> 7;
  const float w00 = w0[o * 3], w01 = w0[o * 3 + 1], w02 = w0[o * 3 + 2];
  const float w10 = w1[o * 3], w11 = w1[o * 3 + 1], w12 = w1[o * 3 + 2];
  const float bb0 = b0[o], bb1 = b1[o];
  for (int m = half; m < TM; m += 2) {
    float4 lo = *(const float4*)&xa[m][0];
    float4 hi = *(const float4*)&xa[m][4];
    float r = bb0 + hi.z * bb1
            + lo.x * w00 + lo.y * w01 + lo.z * w02
            + lo.w * w10 + hi.x * w11 + hi.y * w12;
    y[(size_t)(v0 + m) * DOUT + o] = f2b(fmaxf(r, 0.f));
  }
}

// ---------------- Fused GCN layer via MFMA (bf16) ----------------
// Gather: full-wave row loads (64 lanes), 4-row interleave -> 16 row loads +
// 4 index loads in flight; CSR indices scalarized via readfirstlane (s_load,
// uniform trip counts, no divergence). Exhausted rows load the cached zero row.
// Pass 0 (self rows from global, W0 half) before the barrier; pass 1 (agg from
// LDS, W1 half) after. Weights pre-swizzled -> contiguous 1 KB B-frag loads.

template <int DIN, bool POOL>
__global__ __launch_bounds__(256, 5) void gcn_mfma_kernel(
    const unsigned short* __restrict__ x, const int* __restrict__ rowptr,
    const int* __restrict__ deg, const int* __restrict__ adj,
    const unsigned short* __restrict__ wswz,
    const float* __restrict__ b0, const float* __restrict__ b1,
    void* __restrict__ out) {
  constexpr int TM = 32;
  constexpr int ROWB = DIN * 2;  // bytes per LDS agg row
  __shared__ __align__(16) char lds[TM * ROWB];
  __shared__ float degs_s[TM];

  const int tid = threadIdx.x;
  const int lane = tid & 63;
  const int wave = tid >> 6;

  int v0, valid, batch;
  if constexpr (POOL) {
    batch = blockIdx.y;
    v0 = batch * kV + blockIdx.x * TM;
    valid = min(TM, kV - (int)blockIdx.x * TM);
  } else {
    batch = 0;
    v0 = blockIdx.x * TM;
    valid = TM;
  }

  auto swz = [&](int row, int off) { return row * ROWB + (off ^ ((row & 7) << 4)); };

  const int4* adjq = reinterpret_cast<const int4*>(adj);
  const int4 Z4 = make_int4(kNV, kNV, kNV, kNV);

  // ---- gather: wave owns rows [wave*8, wave*8+8), two groups of 4 ----
  for (int grp = 0; grp < 2; ++grp) {
    int nq[4], q0s[4];
    int4 ci[4];
#pragma unroll
    for (int r = 0; r < 4; ++r) {
      const int m = wave * 8 + grp * 4 + r;
      const bool live = m < valid;
      const int v = live ? (v0 + m) : v0;
      const int b = rowptr[v];
      const int e = rowptr[v + 1];
      nq[r] = __builtin_amdgcn_readfirstlane(live ? ((e - b) >> 2) : 0);
      q0s[r] = __builtin_amdgcn_readfirstlane(b >> 2);
      if (lane == 0) degs_s[m] = live ? (float)deg[v] : 0.f;
      ci[r] = (nq[r] > 0) ? adjq[q0s[r]] : Z4;
    }
    const int tmax = max(max(nq[0], nq[1]), max(nq[2], nq[3]));

    if constexpr (DIN == 256) {
      const uint2* xr = reinterpret_cast<const uint2*>(x);  // row = 64 uint2
      float a[4][4] = {};
      for (int t = 0; t < tmax; ++t) {
        uint2 rw[4][4];
#pragma unroll
        for (int r = 0; r < 4; ++r) {
          rw[r][0] = xr[(size_t)ci[r].x * 64 + lane];
          rw[r][1] = xr[(size_t)ci[r].y * 64 + lane];
          rw[r][2] = xr[(size_t)ci[r].z * 64 + lane];
          rw[r][3] = xr[(size_t)ci[r].w * 64 + lane];
        }
#pragma unroll
        for (int r = 0; r < 4; ++r)
          ci[r] = (t + 1 < nq[r]) ? adjq[q0s[r] + t + 1] : Z4;
#pragma unroll
        for (int r = 0; r < 4; ++r) {
#pragma unroll
          for (int i = 0; i < 4; ++i) {
            a[r][0] += blo(rw[r][i].x);
            a[r][1] += bhi(rw[r][i].x);
            a[r][2] += blo(rw[r][i].y);
            a[r][3] += bhi(rw[r][i].y);
          }
        }
      }
#pragma unroll
      for (int r = 0; r < 4; ++r) {
        const int m = wave * 8 + grp * 4 + r;
        uint2 pk;
        pk.x = pk2(a[r][0], a[r][1]);
        pk.y = pk2(a[r][2], a[r][3]);
        *(uint2*)(lds + swz(m, lane * 8)) = pk;
      }
    } else {  // DIN == 128
      const unsigned* xr = reinterpret_cast<const unsigned*>(x);  // row = 64 uints
      float a[4][2] = {};
      for (int t = 0; t < tmax; ++t) {
        unsigned rw[4][4];
#pragma unroll
        for (int r = 0; r < 4; ++r) {
          rw[r][0] = xr[(size_t)ci[r].x * 64 + lane];
          rw[r][1] = xr[(size_t)ci[r].y * 64 + lane];
          rw[r][2] = xr[(size_t)ci[r].z * 64 + lane];
          rw[r][3] = xr[(size_t)ci[r].w * 64 + lane];
        }
#pragma unroll
        for (int r = 0; r < 4; ++r)
          ci[r] = (t + 1 < nq[r]) ? adjq[q0s[r] + t + 1] : Z4;
#pragma unroll
        for (int r = 0; r < 4; ++r) {
#pragma unroll
          for (int i = 0; i < 4; ++i) {
            a[r][0] += blo(rw[r][i]);
            a[r][1] += bhi(rw[r][i]);
          }
        }
      }
#pragma unroll
      for (int r = 0; r < 4; ++r) {
        const int m = wave * 8 + grp * 4 + r;
        *(unsigned*)(lds + swz(m, lane * 4)) = pk2(a[r][0], a[r][1]);
      }
    }
  }

  // ---- MFMA: wave -> channels [wave*64, wave*64+64) ----
  const int col = lane & 15;
  const int kgrp = lane >> 4;
  const int cbw = wave * 4;  // channel-block base (16-ch blocks)
  f32x4 acc[2][4] = {};

  // pass 0: self rows straight from global, W0 half (s in [0, DIN/32))
  for (int s = 0; s < DIN / 32; ++s) {
    const int ke = s * 32 + kgrp * 8;
    short8 a0 = {}, a1 = {};
    if constexpr (POOL) {
      if (col < valid)      a0 = *(const short8*)(x + (size_t)(v0 + col) * DIN + ke);
      if (col + 16 < valid) a1 = *(const short8*)(x + (size_t)(v0 + col + 16) * DIN + ke);
    } else {
      a0 = *(const short8*)(x + (size_t)(v0 + col) * DIN + ke);
      a1 = *(const short8*)(x + (size_t)(v0 + col + 16) * DIN + ke);
    }
    const unsigned short* wb = wswz + ((size_t)(s * 16 + cbw) * 64 + lane) * 8;
#pragma unroll
    for (int nf = 0; nf < 4; ++nf) {
      short8 bfrag = *(const short8*)(wb + (size_t)nf * 512);
      acc[0][nf] = __builtin_amdgcn_mfma_f32_16x16x32_bf16(a0, bfrag, acc[0][nf], 0, 0, 0);
      acc[1][nf] = __builtin_amdgcn_mfma_f32_16x16x32_bf16(a1, bfrag, acc[1][nf], 0, 0, 0);
    }
  }

  __syncthreads();

  // pass 1: agg rows from LDS, W1 half (s in [DIN/32, 2*DIN/32))
  for (int s2 = 0; s2 < DIN / 32; ++s2) {
    const int kb = (s2 * 32 + kgrp * 8) * 2;
    short8 a0 = *(const short8*)(lds + swz(col, kb));
    short8 a1 = *(const short8*)(lds + swz(col + 16, kb));
    const unsigned short* wb =
        wswz + ((size_t)((DIN / 32 + s2) * 16 + cbw) * 64 + lane) * 8;
#pragma unroll
    for (int nf = 0; nf < 4; ++nf) {
      short8 bfrag = *(const short8*)(wb + (size_t)nf * 512);
      acc[0][nf] = __builtin_amdgcn_mfma_f32_16x16x32_bf16(a0, bfrag, acc[0][nf], 0, 0, 0);
      acc[1][nf] = __builtin_amdgcn_mfma_f32_16x16x32_bf16(a1, bfrag, acc[1][nf], 0, 0, 0);
    }
  }

  // ---- epilogue: C/D map col=lane&15, row=(lane>>4)*4+reg (+16 for mf=1) ----
  const int rb = kgrp * 4;
  const int obase = wave * 64;
  if constexpr (POOL) {
    float* part = (float*)out;  // [kB][16][256] partial slots
    const int slot = blockIdx.x & 15;
#pragma unroll
    for (int nf = 0; nf < 4; ++nf) {
      int o = obase + nf * 16 + col;
      float bb0 = b0[o], bb1 = b1[o];
      float s = 0.f;
#pragma unroll
      for (int mf = 0; mf < 2; ++mf)
#pragma unroll
        for (int j = 0; j < 4; ++j) {
          int row = mf * 16 + rb + j;
          if (row < valid)
            s += fmaxf(acc[mf][nf][j] + bb0 + degs_s[row] * bb1, 0.f);
        }
      s += __shfl_xor(s, 16);
      s += __shfl_xor(s, 32);
      if (lane < 16)
        atomicAdd(&part[((size_t)batch * 16 + slot) * 256 + o], s * (1.0f / (float)kV));
    }
  } else {
    unsigned short* xn = (unsigned short*)out;
#pragma unroll
    for (int nf = 0; nf < 4; ++nf) {
      int o = obase + nf * 16 + col;
      float bb0 = b0[o], bb1 = b1[o];
#pragma unroll
      for (int mf = 0; mf < 2; ++mf)
#pragma unroll
        for (int j = 0; j < 4; ++j) {
          int row = mf * 16 + rb + j;
          float val = fmaxf(acc[mf][nf][j] + bb0 + degs_s[row] * bb1, 0.f);
          xn[(size_t)(v0 + row) * 256 + o] = f2b(val);
        }
    }
  }
}

// Sum the 16 partial slots per batch into pooled[b][o].
__global__ __launch_bounds__(256) void pool_reduce_kernel(const float* __restrict__ part,
                                                          float* __restrict__ pooled) {
  const int b = blockIdx.x;
  const int o = threadIdx.x;
  float s = 0.f;
#pragma unroll
  for (int k = 0; k < 16; ++k) s += part[((size_t)b * 16 + k) * 256 + o];
  pooled[b * 256 + o] = s;
}

// ---------------- MLP head ----------------

__global__ __launch_bounds__(256) void fc1_kernel(const float* __restrict__ pooled,
                                                  const float* __restrict__ w,
                                                  const float* __restrict__ b,
                                                  float* __restrict__ h) {
  __shared__ float ps[256];
  const int bb = blockIdx.x;
  const int o = blockIdx.y * 256 + threadIdx.x;
  ps[threadIdx.x] = pooled[bb * 256 + threadIdx.x];
  __syncthreads();
  const float4* wr = reinterpret_cast<const float4*>(w + (size_t)o * 256);
  float acc = b[o];
  for (int d4 = 0; d4 < 64; ++d4) {
    float4 wv = wr[d4];
    acc += ps[d4 * 4 + 0] * wv.x + ps[d4 * 4 + 1] * wv.y
         + ps[d4 * 4 + 2] * wv.z + ps[d4 * 4 + 3] * wv.w;
  }
  h[bb * 1024 + o] = fmaxf(acc, 0.f);
}

__global__ __launch_bounds__(64) void fc2_kernel(const float* __restrict__ h,
                                                 const float* __restrict__ w,
                                                 const float* __restrict__ b,
                                                 float* __restrict__ out) {
  const int t = blockIdx.x;  // 0..159
  const int bb = t / 10, c = t % 10;
  const int lane = threadIdx.x;
  const float* hr = h + bb * 1024;
  const float* wr = w + c * 1024;
  float acc = 0.f;
#pragma unroll
  for (int k = 0; k < 16; ++k) acc += hr[k * 64 + lane] * wr[k * 64 + lane];
#pragma unroll
  for (int off = 32; off > 0; off >>= 1) acc += __shfl_xor(acc, off);
  if (lane == 0) out[t] = acc + b[c];
}

}  // namespace

extern "C" void kernel_launch(void* const* d_in, const int* in_sizes, int n_in,
                              void* d_out, int out_size, void* d_ws, size_t ws_size,
                              hipStream_t stream) {
  const float* verts = (const float*)d_in[0];
  const int2*  edges = (const int2*)d_in[1];
  const float* g0w0 = (const float*)d_in[2];
  const float* g0b0 = (const float*)d_in[3];
  const float* g0w1 = (const float*)d_in[4];
  const float* g0b1 = (const float*)d_in[5];
  const float* g1w0 = (const float*)d_in[6];
  const float* g1b0 = (const float*)d_in[7];
  const float* g1w1 = (const float*)d_in[8];
  const float* g1b1 = (const float*)d_in[9];
  const float* g2w0 = (const float*)d_in[10];
  const float* g2b0 = (const float*)d_in[11];
  const float* g2w1 = (const float*)d_in[12];
  const float* g2b1 = (const float*)d_in[13];
  const float* fc1w = (const float*)d_in[14];
  const float* fc1b = (const float*)d_in[15];
  const float* fc2w = (const float*)d_in[16];
  const float* fc2b = (const float*)d_in[17];
  float* outp = (float*)d_out;

  char* p = (char*)d_ws;
  auto alloc = [&](size_t bytes) {
    char* r = p;
    p += (bytes + 255) & ~(size_t)255;
    return r;
  };
  unsigned short* x1   = (unsigned short*)alloc((size_t)(kNV + 1) * 128 * 2);  // +zero row
  unsigned short* x2   = (unsigned short*)alloc((size_t)(kNV + 1) * 256 * 2);  // +zero row
  unsigned short* ws1  = (unsigned short*)alloc((size_t)256 * 256 * 2);  // swizzled [W0|W1]
  unsigned short* ws2  = (unsigned short*)alloc((size_t)256 * 512 * 2);
  int*   deg    = (int*)alloc((size_t)kNV * sizeof(int));
  int*   rowptr = (int*)alloc((size_t)(kNV + 1) * sizeof(int));
  int*   cursor = (int*)alloc((size_t)kNV * sizeof(int));
  int*   adj    = (int*)alloc((size_t)kMaxAdjPad * sizeof(int));
  int*   bsum   = (int*)alloc((size_t)kScanBlocks * sizeof(int));
  int*   boff   = (int*)alloc((size_t)kScanBlocks * sizeof(int));
  float* part   = (float*)alloc((size_t)kB * 16 * 256 * sizeof(float));
  float* pooled = (float*)alloc((size_t)kB * 256 * sizeof(float));
  float* h      = (float*)alloc((size_t)kB * 1024 * sizeof(float));

  hipMemsetAsync(deg, 0, (size_t)kNV * sizeof(int), stream);
  hipMemsetAsync(part, 0, (size_t)kB * 16 * 256 * sizeof(float), stream);
  hipMemsetAsync(x1 + (size_t)kNV * 128, 0, 128 * 2, stream);  // zero row
  hipMemsetAsync(x2 + (size_t)kNV * 256, 0, 256 * 2, stream);  // zero row

  // CSR build, degree-padded to multiples of 4
  count_deg_kernel<<<(kNE + 255) / 256, 256, 0, stream>>>(edges, deg);
  block_sum_kernel<<<kScanBlocks, 256, 0, stream>>>(deg, bsum);
  scan_bsum_kernel<<<1, 1024, 0, stream>>>(bsum, boff, rowptr + kNV);
  write_rowptr_kernel<<<kScanBlocks, 256, 0, stream>>>(deg, boff, rowptr, cursor);
  fill_adj_kernel<<<(kNE + 255) / 256, 256, 0, stream>>>(edges, cursor, adj);
  pad_adj_kernel<<<(kNV + 255) / 256, 256, 0, stream>>>(deg, rowptr, adj);

  // Weight cast + MFMA-fragment swizzle
  prep_wswz_kernel<<<32, 256, 0, stream>>>(g1w0, g1w1, ws1, 128);
  prep_wswz_kernel<<<64, 256, 0, stream>>>(g2w0, g2w1, ws2, 256);

  // GCN layers
  gcn_layer0_kernel<<<kNV / 256, 256, 0, stream>>>(verts, rowptr, deg, adj,
                                                   g0w0, g0b0, g0w1, g0b1, x1);
  gcn_mfma_kernel<128, false><<<kNV / 32, 256, 0, stream>>>(
      x1, rowptr, deg, adj, ws1, g1b0, g1b1, x2);
  gcn_mfma_kernel<256, true><<<dim3((kV + 31) / 32, kB), 256, 0, stream>>>(
      x2, rowptr, deg, adj, ws2, g2b0, g2b1, part);
  pool_reduce_kernel<<<kB, 256, 0, stream>>>(part, pooled);

  // MLP head
  fc1_kernel<<<dim3(kB, 4), 256, 0, stream>>>(pooled, fc1w, fc1b, h);
  fc2_kernel<<<kB * 10, 64, 0, stream>>>(h, fc2w, fc2b, outp);
}